// Round 14
// baseline (369.690 us; speedup 1.0000x reference)
//
#include <hip/hip_runtime.h>
#include <hip/hip_bf16.h>
#include <math.h>

// Problem constants
#define BATCH 2
#define DI 192          // D_INNER
#define NST 16          // D_STATE
#define DTR 6           // DT_RANK
#define KK 2
#define LL 4096
#define CT 512          // timesteps per scan chunk (8 per lane)
#define NCK (LL/CT)     // 8 chunk iterations

// ---------------- pe table: pe[col][c], col=l%64 ----------------
__global__ void pe_kernel(float* __restrict__ pe) {
    int i = blockIdx.x * 256 + threadIdx.x;
    if (i >= 64 * DI) return;
    int col = i / DI, c = i % DI;
    float gx = (float)col / 63.f;
    int m = (c < 96) ? c : (c - 96);
    float invf = expf(-(float)m * (logf(10000.f) / 96.f));
    float ang = gx * invf;
    pe[i] = (c < 96) ? sinf(ang) : cosf(ang);
}

// ---------------- fuse conv partials: grid (12 cgroups, 64 rows, 2 b) --------
__global__ void fusepm_part_kernel(const float* __restrict__ xT, const float* __restrict__ xR,
                                   const float* __restrict__ prox, const float* __restrict__ fw,
                                   float* __restrict__ pbuf) {
    __shared__ float wl[288];
    __shared__ float red[2][4][64];
    int cg = blockIdx.x;
    int row = blockIdx.y;
    int b = blockIdx.z;
    int tid = threadIdx.x;
    if (tid < 288) {
        int cl = (tid % 144) / 9, tap = tid % 9;
        int half = tid / 144;
        wl[tid] = fw[(half * DI + cg * 16 + cl) * 9 + tap];
    }
    __syncthreads();
    int px = tid & 63, g = tid >> 6;
    float aT = 0.f, aR = 0.f, aP = 0.f;
    #pragma unroll
    for (int cc = 0; cc < 4; ++cc) {
        int cl = g * 4 + cc;
        int c = cg * 16 + cl;
        const float* xTb = xT + (size_t)(b * DI + c) * LL;
        const float* xRb = xR + (size_t)(b * DI + c) * LL;
        const float* pb  = prox + (size_t)(b * DI + c) * LL;
        const float* wT = wl + cl * 9;
        const float* wP = wl + 144 + cl * 9;
        #pragma unroll
        for (int ky = 0; ky < 3; ++ky) {
            int yy = row + ky - 1;
            if (yy < 0 || yy > 63) continue;
            #pragma unroll
            for (int kx = 0; kx < 3; ++kx) {
                int xx = px + kx - 1;
                bool in = (xx >= 0 && xx < 64);
                int o = yy * 64 + (in ? xx : 0);
                float mT = in ? xTb[o] : 0.f;
                float mR = in ? xRb[o] : 0.f;
                float mP = in ? pb[o] : 0.f;
                float wTv = wT[ky * 3 + kx], wPv = wP[ky * 3 + kx];
                aT += mT * wTv;
                aR += mR * wTv;
                aP += mP * wPv;
            }
        }
    }
    red[0][g][px] = aT + aP;
    red[1][g][px] = aR + aP;
    __syncthreads();
    if (tid < 128) {
        int X = tid >> 6, x = tid & 63;
        float s = red[X][0][x] + red[X][1][x] + red[X][2][x] + red[X][3][x];
        pbuf[(size_t)(cg * 4 + X * 2 + b) * LL + row * 64 + x] = s;
    }
}

// ---------------- reduce 12 partials -> pm[X*2+b][L] ----------------
__global__ void fusepm_reduce_kernel(const float* __restrict__ pbuf,
                                     const float* __restrict__ fb,
                                     float* __restrict__ pm) {
    int idx = blockIdx.x * 256 + threadIdx.x;
    int Xb = idx >> 12;
    int l = idx & 4095;
    float s = fb[0];
    #pragma unroll
    for (int cg = 0; cg < 12; ++cg)
        s += pbuf[(size_t)(cg * 4 + Xb) * LL + l];
    pm[(size_t)Xb * LL + l] = s;
}

// ---------------- rank-count argsort (stable, index tie-break) ----------------
__global__ __launch_bounds__(256) void rank_sort_kernel(const float* __restrict__ pm,
                                                        int* __restrict__ ord,
                                                        int* __restrict__ inv) {
    __shared__ unsigned int keys[LL];
    __shared__ int cnts[4][64];
    int Xb = blockIdx.y;
    int X = Xb >> 1;
    const float* z = pm + (size_t)Xb * LL;
    int tid = threadIdx.x;
    for (int i = tid; i < LL; i += 256) {
        float v = z[i];
        if (X == 0) v = -v;                  // T branch: descending pm
        int bits = __float_as_int(v);
        keys[i] = (bits < 0) ? ~(unsigned)bits : ((unsigned)bits | 0x80000000u);
    }
    __syncthreads();
    int el = tid & 63;
    int q = tid >> 6;
    int e = blockIdx.x * 64 + el;
    unsigned ui = keys[e];
    int count = 0;
    int j0 = q * (LL / 4);
    #pragma unroll 4
    for (int j = j0; j < j0 + LL / 4; ++j) {
        unsigned uj = keys[j];
        count += (uj < ui) || (uj == ui && j < e);
    }
    cnts[q][el] = count;
    __syncthreads();
    if (tid < 64) {
        int rank = cnts[0][tid] + cnts[1][tid] + cnts[2][tid] + cnts[3][tid];
        int i = blockIdx.x * 64 + tid;
        ord[(size_t)Xb * LL + rank] = i;
        inv[(size_t)Xb * LL + i] = rank;
    }
}

// ---------------- depth weight transpose: wtT[i][j] ----------------
__global__ void wt_transpose_kernel(const float* __restrict__ wde, const float* __restrict__ dpw,
                                    const float* __restrict__ sgw, float* __restrict__ wtT) {
    int idx = blockIdx.x * 256 + threadIdx.x;
    if (idx < 192 * 272) {
        int i = idx / 272, j = idx % 272;
        float v;
        if (j < 192) v = wde[j * DI + i];
        else if (j < 256) v = dpw[(j - 192) * DI + i];
        else v = sgw[(j - 256) * DI + i];
        wtT[idx] = v;
    }
}

// ---------------- transpose NCHW (b,c,l) -> (b,l,c), optionally add pe --------
__global__ void transpose_pe_kernel(const float* __restrict__ in, float* __restrict__ out,
                                    const float* __restrict__ pe, int use_pe) {
    __shared__ float tile[32][33];
    int b = blockIdx.z;
    int l0 = blockIdx.x * 32, c0 = blockIdx.y * 32;
    int tx = threadIdx.x, ty = threadIdx.y;
    #pragma unroll
    for (int r = 0; r < 4; ++r) {
        int c = c0 + ty + r * 8;
        tile[ty + r * 8][tx] = in[(size_t)(b * DI + c) * LL + l0 + tx];
    }
    __syncthreads();
    #pragma unroll
    for (int r = 0; r < 4; ++r) {
        int l = l0 + ty + r * 8;
        int c = c0 + tx;
        float v = tile[tx][ty + r * 8];
        if (use_pe) v += pe[(l & 63) * DI + c];
        out[(size_t)(b * LL + l) * DI + c] = v;
    }
}

// ---------------- depth path: 8 positions/block, transposed weights ----------
__global__ __launch_bounds__(256) void depth_kernel(
        const float* __restrict__ proxt, const float* __restrict__ wtT,
        const float* __restrict__ bde, const float* __restrict__ sgb,
        float* __restrict__ dproj, float* __restrict__ dsig) {
    __shared__ float pvs[8][DI];
    __shared__ float dfs[8][DI];
    int bl0 = blockIdx.x * 8;
    int tid = threadIdx.x;
    for (int t = tid; t < 8 * DI; t += 256)
        pvs[t / DI][t % DI] = proxt[(size_t)bl0 * DI + t];
    __syncthreads();
    if (tid < DI) {
        float acc[8];
        #pragma unroll
        for (int l = 0; l < 8; ++l) acc[l] = 0.f;
        const float* wp = wtT + tid;
        for (int i = 0; i < DI; ++i) {
            float w = wp[i * 272];
            #pragma unroll
            for (int l = 0; l < 8; ++l) acc[l] += w * pvs[l][i];
        }
        float bias = bde[tid];
        #pragma unroll
        for (int l = 0; l < 8; ++l) {
            float v = acc[l] + bias;
            dfs[l][tid] = (v > 0.f) ? v : 0.2f * v;
        }
    }
    __syncthreads();
    if (tid < 160) {
        int o = tid >> 1;
        int ph = (tid & 1) * 4;
        float acc[4] = {0.f, 0.f, 0.f, 0.f};
        const float* wp = wtT + 192 + o;
        for (int i = 0; i < DI; ++i) {
            float w = wp[i * 272];
            #pragma unroll
            for (int p = 0; p < 4; ++p) acc[p] += w * dfs[ph + p][i];
        }
        if (o < 64) {
            #pragma unroll
            for (int p = 0; p < 4; ++p)
                dproj[(size_t)(bl0 + ph + p) * 64 + o] = acc[p];
        } else {
            float bias = sgb[o - 64];
            #pragma unroll
            for (int p = 0; p < 4; ++p) {
                float v = acc[p] + bias;
                v = (v > 0.f) ? v : 0.2f * v;
                dsig[(size_t)(bl0 + ph + p) * NST + (o - 64)] = 1.f / (1.f + __expf(-v));
            }
        }
    }
}

// ---------------- project: BOTH branches, 32 positions/block, 512 threads ----
__global__ __launch_bounds__(512) void project_kernel(
        const float* __restrict__ xpeT, const float* __restrict__ xpeR,
        const int* __restrict__ ord,
        const float* __restrict__ xpw, const float* __restrict__ dtw,
        const float* __restrict__ dtb, const float* __restrict__ dproj,
        const float* __restrict__ dsig, float* __restrict__ dtb2,
        float* __restrict__ dub2, float* __restrict__ bscs2) {
    __shared__ float u[32][196];        // row stride 784B (16B aligned)
    __shared__ float dbl[32][40];
    __shared__ int jarr[32];
    int id = blockIdx.x;
    int chunk = id & 127;
    int k = (id >> 7) & 1;
    int b = (id >> 8) & 1;
    int X = id >> 9;
    const float* xpe = X ? xpeR : xpeT;
    int R = (X * 2 + b) * 2 + k;             // buffer row group [X][b][k]
    int s0 = chunk * 32;
    int tid = threadIdx.x;
    if (tid < 32) {
        int s = s0 + tid;
        jarr[tid] = ord[(size_t)(X * 2 + b) * LL + ((k == 0) ? s : (LL - 1 - s))];
    }
    __syncthreads();
    for (int t = tid; t < 32 * 48; t += 512) {
        int l = t / 48, i4 = t % 48;
        *(float4*)&u[l][i4 * 4] =
            *(const float4*)(xpe + (size_t)(b * LL + jarr[l]) * DI + i4 * 4);
    }
    __syncthreads();
    {
        int og = tid >> 5, sl = tid & 31;    // 16 og-groups x 32 sl
        const float* w0 = xpw + (size_t)(k * 38 + og) * DI;
        const float* w1 = w0 + 16 * DI;
        const float* w2 = w0 + 32 * DI;
        bool has2 = (og < 6);
        float a0 = 0.f, a1 = 0.f, a2 = 0.f;
        for (int i4 = 0; i4 < 48; ++i4) {
            float4 u4 = *(const float4*)&u[sl][i4 * 4];
            float4 x0 = *(const float4*)(w0 + i4 * 4);
            float4 x1 = *(const float4*)(w1 + i4 * 4);
            a0 += x0.x * u4.x + x0.y * u4.y + x0.z * u4.z + x0.w * u4.w;
            a1 += x1.x * u4.x + x1.y * u4.y + x1.z * u4.z + x1.w * u4.w;
            if (has2) {
                float4 x2 = *(const float4*)(w2 + i4 * 4);
                a2 += x2.x * u4.x + x2.y * u4.y + x2.z * u4.z + x2.w * u4.w;
            }
        }
        dbl[sl][og] = a0;
        dbl[sl][og + 16] = a1;
        if (has2) dbl[sl][og + 32] = a2;
    }
    __syncthreads();
    if (tid < 384) {
        int c = tid % 192;
        int h = tid / 192;                   // h=0: s 0..15, h=1: s 16..31
        float w[6];
        #pragma unroll
        for (int r = 0; r < 6; ++r) w[r] = dtw[(k * DI + c) * DTR + r];
        float bias = dtb[k * DI + c];
        float dtl[16], dul[16];
        #pragma unroll
        for (int sl = 0; sl < 16; ++sl) {
            int s = h * 16 + sl;
            float d = bias;
            #pragma unroll
            for (int r = 0; r < 6; ++r) d += w[r] * dbl[s][r];
            float sp = fmaxf(d, 0.f) + __logf(1.f + __expf(-fabsf(d)));
            dtl[sl] = sp;
            dul[sl] = sp * u[s][c];
        }
        size_t base = (size_t)(R * DI + c) * LL + s0 + h * 16;
        #pragma unroll
        for (int g = 0; g < 4; ++g) {
            *(float4*)(dtb2 + base + g * 4) =
                make_float4(dtl[g*4], dtl[g*4+1], dtl[g*4+2], dtl[g*4+3]);
            *(float4*)(dub2 + base + g * 4) =
                make_float4(dul[g*4], dul[g*4+1], dul[g*4+2], dul[g*4+3]);
        }
    }
    {
        int n = tid >> 5, sl = tid & 31;     // 16 n x 32 sl: 128B row writes
        int j = jarr[sl];
        float wv = dsig[(size_t)(b * LL + j) * NST + n];
        float Bo = dbl[sl][6 + n], Co = dbl[sl][22 + n];
        float Bd = dproj[(size_t)(b * LL + j) * 64 + k * 32 + n];
        float Cd = dproj[(size_t)(b * LL + j) * 64 + k * 32 + 16 + n];
        size_t sb = (size_t)(R * 32 + n) * LL + s0 + sl;
        bscs2[sb] = (1.f - wv) * Bo + wv * Bd;
        bscs2[sb + (size_t)16 * LL] = (1.f - wv) * Co + wv * Cd;
    }
}

// ---------------- fused scan: 256 threads, 4 waves x 4 states, both branches -
// grid 1536 = 6 blocks/CU exactly (24 waves <= 32 cap) -> single round.
// exp(d*A) recomputed from shared d[8] (trans pipe has headroom) to keep
// VGPR <= 85 for 6 waves/SIMD.
__global__ __launch_bounds__(256, 6) void scan_fused_kernel(
        const float* __restrict__ dtb2, const float* __restrict__ dub2,
        const float* __restrict__ bscs2, const float* __restrict__ AlogT,
        const float* __restrict__ AlogR, float* __restrict__ y) {
    __shared__ float ypart[2][4][CT + 4];
    int id = blockIdx.x;
    int c = id % DI;
    int bkx = id / DI;                       // 0..7: X*4 + b*2 + k
    int X = bkx >> 2;
    int k = bkx & 1;
    const float* Alog = X ? AlogR : AlogT;
    int w = threadIdx.x >> 6;                // 0..3
    int t = threadIdx.x & 63;
    float A[4];
    #pragma unroll
    for (int q = 0; q < 4; ++q)
        A[q] = -__expf(Alog[(k * DI + c) * NST + w + 4 * q]);
    size_t rowc = (size_t)(bkx * DI + c) * LL;
    const float* dtp = dtb2 + rowc;
    const float* dup = dub2 + rowc;
    const float* bp = bscs2 + (size_t)(bkx * 32 + w) * LL;   // B state w; +4q*LL
    const float* cp = bp + (size_t)16 * LL;                  // C state w; +4q*LL
    float* yrow = y + rowc;
    float Hc[4] = {0.f, 0.f, 0.f, 0.f};
    int off = t * 8;
    for (int ck = 0; ck < NCK; ++ck) {
        int o = ck * CT + off;
        float4 dA = *(const float4*)(dtp + o), dB = *(const float4*)(dtp + o + 4);
        float d[8] = {dA.x, dA.y, dA.z, dA.w, dB.x, dB.y, dB.z, dB.w};
        float4 uA = *(const float4*)(dup + o), uB = *(const float4*)(dup + o + 4);
        float uu[8] = {uA.x, uA.y, uA.z, uA.w, uB.x, uB.y, uB.z, uB.w};
        float z[4][8];
        #pragma unroll
        for (int q = 0; q < 4; ++q) {
            const float* bq = bp + (size_t)(4 * q) * LL;
            float4 Ba = *(const float4*)(bq + o), Bb4 = *(const float4*)(bq + o + 4);
            z[q][0] = uu[0] * Ba.x;  z[q][1] = uu[1] * Ba.y;
            z[q][2] = uu[2] * Ba.z;  z[q][3] = uu[3] * Ba.w;
            z[q][4] = uu[4] * Bb4.x; z[q][5] = uu[5] * Bb4.y;
            z[q][6] = uu[6] * Bb4.z; z[q][7] = uu[7] * Bb4.w;
        }
        float cb[4] = {0.f, 0.f, 0.f, 0.f};
        #pragma unroll
        for (int j = 0; j < 8; ++j) {
            #pragma unroll
            for (int q = 0; q < 4; ++q) {
                float e = __expf(d[j] * A[q]);
                cb[q] = cb[q] * e + z[q][j];
            }
        }
        float S = d[0] + d[1] + d[2] + d[3] + d[4] + d[5] + d[6] + d[7];
        // wave inclusive scan over lane totals
        #pragma unroll
        for (int m = 1; m < 64; m <<= 1) {
            float sS = __shfl_up(S, m);
            float s0 = __shfl_up(cb[0], m);
            float s1 = __shfl_up(cb[1], m);
            float s2 = __shfl_up(cb[2], m);
            float s3 = __shfl_up(cb[3], m);
            if (t >= m) {
                cb[0] += __expf(A[0] * S) * s0;
                cb[1] += __expf(A[1] * S) * s1;
                cb[2] += __expf(A[2] * S) * s2;
                cb[3] += __expf(A[3] * S) * s3;
                S += sS;
            }
        }
        float Sf = __shfl(S, 63);
        float Se = __shfl_up(S, 1);
        float h[4];
        #pragma unroll
        for (int q = 0; q < 4; ++q) {
            float bf = __shfl(cb[q], 63);
            float be = __shfl_up(cb[q], 1);
            float se = (t == 0) ? 0.f : Se;
            if (t == 0) be = 0.f;
            h[q] = __expf(A[q] * se) * Hc[q] + be;
            Hc[q] = __expf(A[q] * Sf) * Hc[q] + bf;
        }
        // replay in two halves (C loaded per half to cap registers)
        #pragma unroll
        for (int half = 0; half < 2; ++half) {
            float C[4][4];
            #pragma unroll
            for (int q = 0; q < 4; ++q) {
                float4 Cv = *(const float4*)(cp + (size_t)(4 * q) * LL + o + half * 4);
                C[q][0] = Cv.x; C[q][1] = Cv.y; C[q][2] = Cv.z; C[q][3] = Cv.w;
            }
            float yv[4];
            #pragma unroll
            for (int j = 0; j < 4; ++j) {
                int jj = half * 4 + j;
                float acc = 0.f;
                #pragma unroll
                for (int q = 0; q < 4; ++q) {
                    float e = __expf(d[jj] * A[q]);
                    h[q] = h[q] * e + z[q][jj];
                    acc += h[q] * C[q][j];
                }
                yv[j] = acc;
            }
            *(float4*)&ypart[ck & 1][w][off + half * 4] =
                make_float4(yv[0], yv[1], yv[2], yv[3]);
        }
        __syncthreads();
        if (threadIdx.x < 128) {
            int t4 = threadIdx.x * 4;
            float4 s = *(const float4*)&ypart[ck & 1][0][t4];
            #pragma unroll
            for (int r = 1; r < 4; ++r) {
                float4 v = *(const float4*)&ypart[ck & 1][r][t4];
                s.x += v.x; s.y += v.y; s.z += v.z; s.w += v.w;
            }
            *(float4*)(yrow + ck * CT + t4) = s;
        }
        // next iter writes ypart[(ck+1)&1] -> no second barrier needed
    }
}

// ---------------- s-order gather + D*u + layernorm + output, both branches ---
__global__ __launch_bounds__(256) void ln_kernel(const float* __restrict__ y,
                          const float* __restrict__ xpeT, const float* __restrict__ xpeR,
                          const int* __restrict__ ord, const float* __restrict__ DvT,
                          const float* __restrict__ DvR, const float* __restrict__ g,
                          const float* __restrict__ beta, float* __restrict__ out) {
    __shared__ float y0t[DI][17];
    __shared__ float y1t[DI][17];
    int id = blockIdx.x;
    int X = id >> 9;
    int b = (id >> 8) & 1;
    int s0 = (id & 255) * 16;
    const float* xpe = X ? xpeR : xpeT;
    const float* Dvec = X ? DvR : DvT;
    int R0 = (X * 2 + b) * 2;
    int tid = threadIdx.x;
    for (int idx = tid; idx < DI * 16; idx += 256) {
        int c = idx >> 4, j = idx & 15;
        y0t[c][j] = y[((size_t)(R0 + 0) * DI + c) * LL + s0 + j];
        y1t[c][j] = y[((size_t)(R0 + 1) * DI + c) * LL + (LL - 1 - s0 - j)];
    }
    __syncthreads();
    int w = tid >> 6, lane = tid & 63;
    #pragma unroll
    for (int it = 0; it < 4; ++it) {
        int j = it * 4 + w;
        int l = ord[(size_t)(X * 2 + b) * LL + s0 + j];
        const float* xr = xpe + (size_t)(b * LL + l) * DI;
        float v[3];
        float sum = 0.f, sq = 0.f;
        #pragma unroll
        for (int r = 0; r < 3; ++r) {
            int c = lane + r * 64;
            float t = y0t[c][j] + y1t[c][j] + (Dvec[c] + Dvec[DI + c]) * xr[c];
            v[r] = t; sum += t; sq += t * t;
        }
        #pragma unroll
        for (int m = 1; m < 64; m <<= 1) {
            sum += __shfl_xor(sum, m);
            sq += __shfl_xor(sq, m);
        }
        float mu = sum * (1.f / 192.f);
        float var = sq * (1.f / 192.f) - mu * mu;
        float rs = rsqrtf(var + 1e-5f);
        float* op = out + ((size_t)(X * 2 + b) * LL + l) * DI;
        #pragma unroll
        for (int r = 0; r < 3; ++r) {
            int c = lane + r * 64;
            op[c] = (v[r] - mu) * rs * g[c] + beta[c];
        }
    }
}

extern "C" void kernel_launch(void* const* d_in, const int* in_sizes, int n_in,
                              void* d_out, int out_size, void* d_ws, size_t ws_size,
                              hipStream_t stream) {
    const float* x_T = (const float*)d_in[0];
    const float* x_R = (const float*)d_in[1];
    const float* prox = (const float*)d_in[2];
    const float* fuse_w = (const float*)d_in[3];
    const float* fuse_b = (const float*)d_in[4];
    const float* x_proj_w = (const float*)d_in[5];
    const float* dt_w = (const float*)d_in[6];
    const float* dt_b = (const float*)d_in[7];
    const float* A_log_T = (const float*)d_in[8];
    const float* A_log_R = (const float*)d_in[9];
    const float* D_T = (const float*)d_in[10];
    const float* D_R = (const float*)d_in[11];
    const float* depth_enc_w = (const float*)d_in[12];
    const float* depth_enc_b = (const float*)d_in[13];
    const float* depth_proj_w = (const float*)d_in[14];
    const float* sig_w = (const float*)d_in[15];
    const float* sig_b = (const float*)d_in[16];
    const float* ln_g = (const float*)d_in[17];
    const float* ln_b = (const float*)d_in[18];
    float* out = (float*)d_out;
    char* ws = (char*)d_ws;

    // ws_size = 256 MiB (measured via harness poison fill). Layout:
    float* pe    = (float*)(ws + 0);         //    49152
    float* pm    = (float*)(ws + 49152);     //    65536
    int*   ord   = (int*)(ws + 114688);      //    65536
    int*   inv   = (int*)(ws + 180224);      //    65536
    float* proxt = (float*)(ws + 245760);    //  6291456 (dead after depth -> xpeR)
    float* dproj = (float*)(ws + 6537216);   //  2097152
    float* dsig  = (float*)(ws + 8634368);   //   524288
    float* xpeT  = (float*)(ws + 9158656);   //  6291456
    float* dtb2  = (float*)(ws + 15450112);  // 25165824  [X][b][k][c][s]
    float* dub2  = (float*)(ws + 40615936);  // 25165824
    float* bscs2 = (float*)(ws + 65781760);  //  4194304  [X][b][k][n][s]
    float* ybuf  = (float*)(ws + 69976064);  // 25165824  [X][b][k][c][s] -> 95.1 MB
    float* xpeR  = proxt;                    // aliases proxt (dead after depth)
    float* pbuf  = dtb2;                     // fuse partials (dead until project)
    float* wtT   = bscs2;                    // 209 KB (dead once project writes)

    pe_kernel<<<48, 256, 0, stream>>>(pe);
    fusepm_part_kernel<<<dim3(12, 64, 2), 256, 0, stream>>>(x_T, x_R, prox, fuse_w, pbuf);
    fusepm_reduce_kernel<<<64, 256, 0, stream>>>(pbuf, fuse_b, pm);
    rank_sort_kernel<<<dim3(64, 4), 256, 0, stream>>>(pm, ord, inv);
    wt_transpose_kernel<<<204, 256, 0, stream>>>(depth_enc_w, depth_proj_w, sig_w, wtT);
    transpose_pe_kernel<<<dim3(128, 6, 2), dim3(32, 8), 0, stream>>>(prox, proxt, pe, 0);
    depth_kernel<<<1024, 256, 0, stream>>>(proxt, wtT, depth_enc_b, sig_b, dproj, dsig);
    transpose_pe_kernel<<<dim3(128, 6, 2), dim3(32, 8), 0, stream>>>(x_T, xpeT, pe, 1);
    transpose_pe_kernel<<<dim3(128, 6, 2), dim3(32, 8), 0, stream>>>(x_R, xpeR, pe, 1);
    project_kernel<<<1024, 512, 0, stream>>>(xpeT, xpeR, ord, x_proj_w, dt_w, dt_b,
                                             dproj, dsig, dtb2, dub2, bscs2);
    scan_fused_kernel<<<8 * DI, 256, 0, stream>>>(dtb2, dub2, bscs2, A_log_T, A_log_R, ybuf);
    ln_kernel<<<1024, 256, 0, stream>>>(ybuf, xpeT, xpeR, ord, D_T, D_R, ln_g, ln_b, out);
}

// Round 15
// 212.349 us; speedup vs baseline: 1.7410x; 1.7410x over previous
//
#include <hip/hip_runtime.h>
#include <hip/hip_bf16.h>
#include <math.h>

// Problem constants
#define BATCH 2
#define DI 192          // D_INNER
#define NST 16          // D_STATE
#define DTR 6           // DT_RANK
#define KK 2
#define LL 4096
#define CT 512          // timesteps per scan chunk (8 per lane)
#define NCK (LL/CT)     // 8 chunk iterations

// ---------------- pe table + depth weight transpose (merged) ----------------
// blocks 0..47: pe[col][c]; blocks 48..251: wtT[i][j]
__global__ void pe_wt_kernel(float* __restrict__ pe,
                             const float* __restrict__ wde, const float* __restrict__ dpw,
                             const float* __restrict__ sgw, float* __restrict__ wtT) {
    if (blockIdx.x < 48) {
        int i = blockIdx.x * 256 + threadIdx.x;
        if (i >= 64 * DI) return;
        int col = i / DI, c = i % DI;
        float gx = (float)col / 63.f;
        int m = (c < 96) ? c : (c - 96);
        float invf = expf(-(float)m * (logf(10000.f) / 96.f));
        float ang = gx * invf;
        pe[i] = (c < 96) ? sinf(ang) : cosf(ang);
    } else {
        int idx = (blockIdx.x - 48) * 256 + threadIdx.x;
        if (idx < 192 * 272) {
            int i = idx / 272, j = idx % 272;
            float v;
            if (j < 192) v = wde[j * DI + i];
            else if (j < 256) v = dpw[(j - 192) * DI + i];
            else v = sgw[(j - 256) * DI + i];
            wtT[idx] = v;
        }
    }
}

// ---------------- fuse conv partials: grid (12 cgroups, 64 rows, 2 b) --------
__global__ void fusepm_part_kernel(const float* __restrict__ xT, const float* __restrict__ xR,
                                   const float* __restrict__ prox, const float* __restrict__ fw,
                                   float* __restrict__ pbuf) {
    __shared__ float wl[288];
    __shared__ float red[2][4][64];
    int cg = blockIdx.x;
    int row = blockIdx.y;
    int b = blockIdx.z;
    int tid = threadIdx.x;
    if (tid < 288) {
        int cl = (tid % 144) / 9, tap = tid % 9;
        int half = tid / 144;
        wl[tid] = fw[(half * DI + cg * 16 + cl) * 9 + tap];
    }
    __syncthreads();
    int px = tid & 63, g = tid >> 6;
    float aT = 0.f, aR = 0.f, aP = 0.f;
    #pragma unroll
    for (int cc = 0; cc < 4; ++cc) {
        int cl = g * 4 + cc;
        int c = cg * 16 + cl;
        const float* xTb = xT + (size_t)(b * DI + c) * LL;
        const float* xRb = xR + (size_t)(b * DI + c) * LL;
        const float* pb  = prox + (size_t)(b * DI + c) * LL;
        const float* wT = wl + cl * 9;
        const float* wP = wl + 144 + cl * 9;
        #pragma unroll
        for (int ky = 0; ky < 3; ++ky) {
            int yy = row + ky - 1;
            if (yy < 0 || yy > 63) continue;
            #pragma unroll
            for (int kx = 0; kx < 3; ++kx) {
                int xx = px + kx - 1;
                bool in = (xx >= 0 && xx < 64);
                int o = yy * 64 + (in ? xx : 0);
                float mT = in ? xTb[o] : 0.f;
                float mR = in ? xRb[o] : 0.f;
                float mP = in ? pb[o] : 0.f;
                float wTv = wT[ky * 3 + kx], wPv = wP[ky * 3 + kx];
                aT += mT * wTv;
                aR += mR * wTv;
                aP += mP * wPv;
            }
        }
    }
    red[0][g][px] = aT + aP;
    red[1][g][px] = aR + aP;
    __syncthreads();
    if (tid < 128) {
        int X = tid >> 6, x = tid & 63;
        float s = red[X][0][x] + red[X][1][x] + red[X][2][x] + red[X][3][x];
        pbuf[(size_t)(cg * 4 + X * 2 + b) * LL + row * 64 + x] = s;
    }
}

// ---------------- rank-count argsort with inline 12-partial reduction --------
// grid (64, 4): blockIdx.y = Xb = X*2+b. Stages keys (reduced from pbuf) in
// LDS as sortable-uint; rank = #{j : k[j]<k[i] or (== and j<i)}.
__global__ __launch_bounds__(256) void rank_sort_kernel(const float* __restrict__ pbuf,
                                                        const float* __restrict__ fb,
                                                        int* __restrict__ ord,
                                                        int* __restrict__ inv) {
    __shared__ unsigned int keys[LL];
    __shared__ int cnts[4][64];
    int Xb = blockIdx.y;
    int X = Xb >> 1;
    int tid = threadIdx.x;
    float bias = fb[0];
    for (int i = tid; i < LL; i += 256) {
        float v = bias;
        #pragma unroll
        for (int cg = 0; cg < 12; ++cg)
            v += pbuf[(size_t)(cg * 4 + Xb) * LL + i];
        if (X == 0) v = -v;                  // T branch: descending pm
        int bits = __float_as_int(v);
        keys[i] = (bits < 0) ? ~(unsigned)bits : ((unsigned)bits | 0x80000000u);
    }
    __syncthreads();
    int el = tid & 63;
    int q = tid >> 6;
    int e = blockIdx.x * 64 + el;
    unsigned ui = keys[e];
    int count = 0;
    int j0 = q * (LL / 4);
    #pragma unroll 4
    for (int j = j0; j < j0 + LL / 4; ++j) {
        unsigned uj = keys[j];
        count += (uj < ui) || (uj == ui && j < e);
    }
    cnts[q][el] = count;
    __syncthreads();
    if (tid < 64) {
        int rank = cnts[0][tid] + cnts[1][tid] + cnts[2][tid] + cnts[3][tid];
        int i = blockIdx.x * 64 + tid;
        ord[(size_t)Xb * LL + rank] = i;
        inv[(size_t)Xb * LL + i] = rank;
    }
}

// ---------------- transpose NCHW (b,c,l) -> (b,l,c), optionally add pe --------
__global__ void transpose_pe_kernel(const float* __restrict__ in, float* __restrict__ out,
                                    const float* __restrict__ pe, int use_pe) {
    __shared__ float tile[32][33];
    int b = blockIdx.z;
    int l0 = blockIdx.x * 32, c0 = blockIdx.y * 32;
    int tx = threadIdx.x, ty = threadIdx.y;
    #pragma unroll
    for (int r = 0; r < 4; ++r) {
        int c = c0 + ty + r * 8;
        tile[ty + r * 8][tx] = in[(size_t)(b * DI + c) * LL + l0 + tx];
    }
    __syncthreads();
    #pragma unroll
    for (int r = 0; r < 4; ++r) {
        int l = l0 + ty + r * 8;
        int c = c0 + tx;
        float v = tile[tx][ty + r * 8];
        if (use_pe) v += pe[(l & 63) * DI + c];
        out[(size_t)(b * LL + l) * DI + c] = v;
    }
}

// ---------------- depth path: 8 positions/block, transposed weights ----------
__global__ __launch_bounds__(256) void depth_kernel(
        const float* __restrict__ proxt, const float* __restrict__ wtT,
        const float* __restrict__ bde, const float* __restrict__ sgb,
        float* __restrict__ dproj, float* __restrict__ dsig) {
    __shared__ float pvs[8][DI];
    __shared__ float dfs[8][DI];
    int bl0 = blockIdx.x * 8;
    int tid = threadIdx.x;
    for (int t = tid; t < 8 * DI; t += 256)
        pvs[t / DI][t % DI] = proxt[(size_t)bl0 * DI + t];
    __syncthreads();
    if (tid < DI) {
        float acc[8];
        #pragma unroll
        for (int l = 0; l < 8; ++l) acc[l] = 0.f;
        const float* wp = wtT + tid;
        for (int i = 0; i < DI; ++i) {
            float w = wp[i * 272];
            #pragma unroll
            for (int l = 0; l < 8; ++l) acc[l] += w * pvs[l][i];
        }
        float bias = bde[tid];
        #pragma unroll
        for (int l = 0; l < 8; ++l) {
            float v = acc[l] + bias;
            dfs[l][tid] = (v > 0.f) ? v : 0.2f * v;
        }
    }
    __syncthreads();
    if (tid < 160) {
        int o = tid >> 1;
        int ph = (tid & 1) * 4;
        float acc[4] = {0.f, 0.f, 0.f, 0.f};
        const float* wp = wtT + 192 + o;
        for (int i = 0; i < DI; ++i) {
            float w = wp[i * 272];
            #pragma unroll
            for (int p = 0; p < 4; ++p) acc[p] += w * dfs[ph + p][i];
        }
        if (o < 64) {
            #pragma unroll
            for (int p = 0; p < 4; ++p)
                dproj[(size_t)(bl0 + ph + p) * 64 + o] = acc[p];
        } else {
            float bias = sgb[o - 64];
            #pragma unroll
            for (int p = 0; p < 4; ++p) {
                float v = acc[p] + bias;
                v = (v > 0.f) ? v : 0.2f * v;
                dsig[(size_t)(bl0 + ph + p) * NST + (o - 64)] = 1.f / (1.f + __expf(-v));
            }
        }
    }
}

// ---------------- project: BOTH branches, 32 positions/block, 512 threads ----
__global__ __launch_bounds__(512) void project_kernel(
        const float* __restrict__ xpeT, const float* __restrict__ xpeR,
        const int* __restrict__ ord,
        const float* __restrict__ xpw, const float* __restrict__ dtw,
        const float* __restrict__ dtb, const float* __restrict__ dproj,
        const float* __restrict__ dsig, float* __restrict__ dtb2,
        float* __restrict__ dub2, float* __restrict__ bscs2) {
    __shared__ float u[32][196];        // row stride 784B (16B aligned)
    __shared__ float dbl[32][40];
    __shared__ int jarr[32];
    int id = blockIdx.x;
    int chunk = id & 127;
    int k = (id >> 7) & 1;
    int b = (id >> 8) & 1;
    int X = id >> 9;
    const float* xpe = X ? xpeR : xpeT;
    int R = (X * 2 + b) * 2 + k;             // buffer row group [X][b][k]
    int s0 = chunk * 32;
    int tid = threadIdx.x;
    if (tid < 32) {
        int s = s0 + tid;
        jarr[tid] = ord[(size_t)(X * 2 + b) * LL + ((k == 0) ? s : (LL - 1 - s))];
    }
    __syncthreads();
    for (int t = tid; t < 32 * 48; t += 512) {
        int l = t / 48, i4 = t % 48;
        *(float4*)&u[l][i4 * 4] =
            *(const float4*)(xpe + (size_t)(b * LL + jarr[l]) * DI + i4 * 4);
    }
    __syncthreads();
    {
        int og = tid >> 5, sl = tid & 31;    // 16 og-groups x 32 sl
        const float* w0 = xpw + (size_t)(k * 38 + og) * DI;
        const float* w1 = w0 + 16 * DI;
        const float* w2 = w0 + 32 * DI;
        bool has2 = (og < 6);
        float a0 = 0.f, a1 = 0.f, a2 = 0.f;
        for (int i4 = 0; i4 < 48; ++i4) {
            float4 u4 = *(const float4*)&u[sl][i4 * 4];
            float4 x0 = *(const float4*)(w0 + i4 * 4);
            float4 x1 = *(const float4*)(w1 + i4 * 4);
            a0 += x0.x * u4.x + x0.y * u4.y + x0.z * u4.z + x0.w * u4.w;
            a1 += x1.x * u4.x + x1.y * u4.y + x1.z * u4.z + x1.w * u4.w;
            if (has2) {
                float4 x2 = *(const float4*)(w2 + i4 * 4);
                a2 += x2.x * u4.x + x2.y * u4.y + x2.z * u4.z + x2.w * u4.w;
            }
        }
        dbl[sl][og] = a0;
        dbl[sl][og + 16] = a1;
        if (has2) dbl[sl][og + 32] = a2;
    }
    __syncthreads();
    if (tid < 384) {
        int c = tid % 192;
        int h = tid / 192;                   // h=0: s 0..15, h=1: s 16..31
        float w[6];
        #pragma unroll
        for (int r = 0; r < 6; ++r) w[r] = dtw[(k * DI + c) * DTR + r];
        float bias = dtb[k * DI + c];
        float dtl[16], dul[16];
        #pragma unroll
        for (int sl = 0; sl < 16; ++sl) {
            int s = h * 16 + sl;
            float d = bias;
            #pragma unroll
            for (int r = 0; r < 6; ++r) d += w[r] * dbl[s][r];
            float sp = fmaxf(d, 0.f) + __logf(1.f + __expf(-fabsf(d)));
            dtl[sl] = sp;
            dul[sl] = sp * u[s][c];
        }
        size_t base = (size_t)(R * DI + c) * LL + s0 + h * 16;
        #pragma unroll
        for (int g = 0; g < 4; ++g) {
            *(float4*)(dtb2 + base + g * 4) =
                make_float4(dtl[g*4], dtl[g*4+1], dtl[g*4+2], dtl[g*4+3]);
            *(float4*)(dub2 + base + g * 4) =
                make_float4(dul[g*4], dul[g*4+1], dul[g*4+2], dul[g*4+3]);
        }
    }
    {
        int n = tid >> 5, sl = tid & 31;     // 16 n x 32 sl: 128B row writes
        int j = jarr[sl];
        float wv = dsig[(size_t)(b * LL + j) * NST + n];
        float Bo = dbl[sl][6 + n], Co = dbl[sl][22 + n];
        float Bd = dproj[(size_t)(b * LL + j) * 64 + k * 32 + n];
        float Cd = dproj[(size_t)(b * LL + j) * 64 + k * 32 + 16 + n];
        size_t sb = (size_t)(R * 32 + n) * LL + s0 + sl;
        bscs2[sb] = (1.f - wv) * Bo + wv * Bd;
        bscs2[sb + (size_t)16 * LL] = (1.f - wv) * Co + wv * Cd;
    }
}

// ---------------- fused scan (round-13 proven version): 512 thr, 8w x 2 states
__global__ __launch_bounds__(512, 6) void scan_fused_kernel(
        const float* __restrict__ dtb2, const float* __restrict__ dub2,
        const float* __restrict__ bscs2, const float* __restrict__ AlogT,
        const float* __restrict__ AlogR, float* __restrict__ y) {
    __shared__ float ypart[2][8][CT + 4];
    int id = blockIdx.x;
    int c = id % DI;
    int bkx = id / DI;                       // 0..7: X*4 + b*2 + k
    int X = bkx >> 2;
    int k = bkx & 1;
    const float* Alog = X ? AlogR : AlogT;
    int w = threadIdx.x >> 6;
    int t = threadIdx.x & 63;
    float A0 = -__expf(Alog[(k * DI + c) * NST + w]);
    float A1 = -__expf(Alog[(k * DI + c) * NST + w + 8]);
    size_t rowc = (size_t)(bkx * DI + c) * LL;
    const float* dtp = dtb2 + rowc;
    const float* dup = dub2 + rowc;
    const float* b0p = bscs2 + (size_t)(bkx * 32 + w) * LL;
    const float* c0p = b0p + (size_t)16 * LL;
    const float* b1p = b0p + (size_t)8 * LL;
    const float* c1p = c0p + (size_t)8 * LL;
    float* yrow = y + rowc;
    float Hc0 = 0.f, Hc1 = 0.f;
    int off = t * 8;
    for (int ck = 0; ck < NCK; ++ck) {
        int base = ck * CT;
        int o = base + off;
        float4 dA = *(const float4*)(dtp + o), dB = *(const float4*)(dtp + o + 4);
        float4 uA = *(const float4*)(dup + o), uB = *(const float4*)(dup + o + 4);
        float4 B0a = *(const float4*)(b0p + o), B0b = *(const float4*)(b0p + o + 4);
        float4 B1a = *(const float4*)(b1p + o), B1b = *(const float4*)(b1p + o + 4);
        float d[8]  = {dA.x, dA.y, dA.z, dA.w, dB.x, dB.y, dB.z, dB.w};
        float uu[8] = {uA.x, uA.y, uA.z, uA.w, uB.x, uB.y, uB.z, uB.w};
        float Bb0[8] = {B0a.x, B0a.y, B0a.z, B0a.w, B0b.x, B0b.y, B0b.z, B0b.w};
        float Bb1[8] = {B1a.x, B1a.y, B1a.z, B1a.w, B1b.x, B1b.y, B1b.z, B1b.w};
        float e0[8], e1[8], z0[8], z1[8];
        float S = 0.f, cb0 = 0.f, cb1 = 0.f;
        #pragma unroll
        for (int j = 0; j < 8; ++j) {
            e0[j] = __expf(d[j] * A0);
            e1[j] = __expf(d[j] * A1);
            z0[j] = uu[j] * Bb0[j];
            z1[j] = uu[j] * Bb1[j];
            S += d[j];
            cb0 = cb0 * e0[j] + z0[j];
            cb1 = cb1 * e1[j] + z1[j];
        }
        #pragma unroll
        for (int m = 1; m < 64; m <<= 1) {
            float sS = __shfl_up(S, m);
            float s0 = __shfl_up(cb0, m);
            float s1 = __shfl_up(cb1, m);
            if (t >= m) {
                cb0 += __expf(A0 * S) * s0;
                cb1 += __expf(A1 * S) * s1;
                S += sS;
            }
        }
        float Sf  = __shfl(S, 63);
        float b0f = __shfl(cb0, 63);
        float b1f = __shfl(cb1, 63);
        float Se  = __shfl_up(S, 1);
        float b0e = __shfl_up(cb0, 1);
        float b1e = __shfl_up(cb1, 1);
        if (t == 0) { Se = 0.f; b0e = 0.f; b1e = 0.f; }
        float h0 = __expf(A0 * Se) * Hc0 + b0e;
        float h1 = __expf(A1 * Se) * Hc1 + b1e;
        float nHc0 = __expf(A0 * Sf) * Hc0 + b0f;
        float nHc1 = __expf(A1 * Sf) * Hc1 + b1f;
        Hc0 = nHc0; Hc1 = nHc1;
        float4 C0a = *(const float4*)(c0p + o), C0b = *(const float4*)(c0p + o + 4);
        float4 C1a = *(const float4*)(c1p + o), C1b = *(const float4*)(c1p + o + 4);
        float Cc0[8] = {C0a.x, C0a.y, C0a.z, C0a.w, C0b.x, C0b.y, C0b.z, C0b.w};
        float Cc1[8] = {C1a.x, C1a.y, C1a.z, C1a.w, C1b.x, C1b.y, C1b.z, C1b.w};
        float yv[8];
        #pragma unroll
        for (int j = 0; j < 8; ++j) {
            h0 = h0 * e0[j] + z0[j];
            h1 = h1 * e1[j] + z1[j];
            yv[j] = h0 * Cc0[j] + h1 * Cc1[j];
        }
        *(float4*)&ypart[ck & 1][w][off] = make_float4(yv[0], yv[1], yv[2], yv[3]);
        *(float4*)&ypart[ck & 1][w][off + 4] = make_float4(yv[4], yv[5], yv[6], yv[7]);
        __syncthreads();
        if (threadIdx.x < 128) {
            int t4 = threadIdx.x * 4;
            float4 s = *(const float4*)&ypart[ck & 1][0][t4];
            #pragma unroll
            for (int r = 1; r < 8; ++r) {
                float4 v = *(const float4*)&ypart[ck & 1][r][t4];
                s.x += v.x; s.y += v.y; s.z += v.z; s.w += v.w;
            }
            *(float4*)(yrow + base + t4) = s;
        }
    }
}

// ---------------- s-order gather + D*u + layernorm + output, both branches ---
__global__ __launch_bounds__(256) void ln_kernel(const float* __restrict__ y,
                          const float* __restrict__ xpeT, const float* __restrict__ xpeR,
                          const int* __restrict__ ord, const float* __restrict__ DvT,
                          const float* __restrict__ DvR, const float* __restrict__ g,
                          const float* __restrict__ beta, float* __restrict__ out) {
    __shared__ float y0t[DI][17];
    __shared__ float y1t[DI][17];
    int id = blockIdx.x;
    int X = id >> 9;
    int b = (id >> 8) & 1;
    int s0 = (id & 255) * 16;
    const float* xpe = X ? xpeR : xpeT;
    const float* Dvec = X ? DvR : DvT;
    int R0 = (X * 2 + b) * 2;
    int tid = threadIdx.x;
    for (int idx = tid; idx < DI * 16; idx += 256) {
        int c = idx >> 4, j = idx & 15;
        y0t[c][j] = y[((size_t)(R0 + 0) * DI + c) * LL + s0 + j];
        y1t[c][j] = y[((size_t)(R0 + 1) * DI + c) * LL + (LL - 1 - s0 - j)];
    }
    __syncthreads();
    int w = tid >> 6, lane = tid & 63;
    #pragma unroll
    for (int it = 0; it < 4; ++it) {
        int j = it * 4 + w;
        int l = ord[(size_t)(X * 2 + b) * LL + s0 + j];
        const float* xr = xpe + (size_t)(b * LL + l) * DI;
        float v[3];
        float sum = 0.f, sq = 0.f;
        #pragma unroll
        for (int r = 0; r < 3; ++r) {
            int c = lane + r * 64;
            float t = y0t[c][j] + y1t[c][j] + (Dvec[c] + Dvec[DI + c]) * xr[c];
            v[r] = t; sum += t; sq += t * t;
        }
        #pragma unroll
        for (int m = 1; m < 64; m <<= 1) {
            sum += __shfl_xor(sum, m);
            sq += __shfl_xor(sq, m);
        }
        float mu = sum * (1.f / 192.f);
        float var = sq * (1.f / 192.f) - mu * mu;
        float rs = rsqrtf(var + 1e-5f);
        float* op = out + ((size_t)(X * 2 + b) * LL + l) * DI;
        #pragma unroll
        for (int r = 0; r < 3; ++r) {
            int c = lane + r * 64;
            op[c] = (v[r] - mu) * rs * g[c] + beta[c];
        }
    }
}

extern "C" void kernel_launch(void* const* d_in, const int* in_sizes, int n_in,
                              void* d_out, int out_size, void* d_ws, size_t ws_size,
                              hipStream_t stream) {
    const float* x_T = (const float*)d_in[0];
    const float* x_R = (const float*)d_in[1];
    const float* prox = (const float*)d_in[2];
    const float* fuse_w = (const float*)d_in[3];
    const float* fuse_b = (const float*)d_in[4];
    const float* x_proj_w = (const float*)d_in[5];
    const float* dt_w = (const float*)d_in[6];
    const float* dt_b = (const float*)d_in[7];
    const float* A_log_T = (const float*)d_in[8];
    const float* A_log_R = (const float*)d_in[9];
    const float* D_T = (const float*)d_in[10];
    const float* D_R = (const float*)d_in[11];
    const float* depth_enc_w = (const float*)d_in[12];
    const float* depth_enc_b = (const float*)d_in[13];
    const float* depth_proj_w = (const float*)d_in[14];
    const float* sig_w = (const float*)d_in[15];
    const float* sig_b = (const float*)d_in[16];
    const float* ln_g = (const float*)d_in[17];
    const float* ln_b = (const float*)d_in[18];
    float* out = (float*)d_out;
    char* ws = (char*)d_ws;

    // ws_size = 256 MiB. Layout:
    float* pe    = (float*)(ws + 0);         //    49152
    int*   ord   = (int*)(ws + 114688);      //    65536
    int*   inv   = (int*)(ws + 180224);      //    65536
    float* proxt = (float*)(ws + 245760);    //  6291456 (dead after depth -> xpeR)
    float* dproj = (float*)(ws + 6537216);   //  2097152
    float* dsig  = (float*)(ws + 8634368);   //   524288
    float* xpeT  = (float*)(ws + 9158656);   //  6291456
    float* dtb2  = (float*)(ws + 15450112);  // 25165824  [X][b][k][c][s]
    float* dub2  = (float*)(ws + 40615936);  // 25165824
    float* bscs2 = (float*)(ws + 65781760);  //  4194304  [X][b][k][n][s]
    float* ybuf  = (float*)(ws + 69976064);  // 25165824  [X][b][k][c][s]
    float* xpeR  = proxt;                    // aliases proxt (dead after depth)
    float* pbuf  = dtb2;                     // fuse partials (dead until project)
    float* wtT   = bscs2;                    // 209 KB (dead once project writes)

    pe_wt_kernel<<<252, 256, 0, stream>>>(pe, depth_enc_w, depth_proj_w, sig_w, wtT);
    fusepm_part_kernel<<<dim3(12, 64, 2), 256, 0, stream>>>(x_T, x_R, prox, fuse_w, pbuf);
    rank_sort_kernel<<<dim3(64, 4), 256, 0, stream>>>(pbuf, fuse_b, ord, inv);
    transpose_pe_kernel<<<dim3(128, 6, 2), dim3(32, 8), 0, stream>>>(prox, proxt, pe, 0);
    depth_kernel<<<1024, 256, 0, stream>>>(proxt, wtT, depth_enc_b, sig_b, dproj, dsig);
    transpose_pe_kernel<<<dim3(128, 6, 2), dim3(32, 8), 0, stream>>>(x_T, xpeT, pe, 1);
    transpose_pe_kernel<<<dim3(128, 6, 2), dim3(32, 8), 0, stream>>>(x_R, xpeR, pe, 1);
    project_kernel<<<1024, 512, 0, stream>>>(xpeT, xpeR, ord, x_proj_w, dt_w, dt_b,
                                             dproj, dsig, dtb2, dub2, bscs2);
    scan_fused_kernel<<<8 * DI, 512, 0, stream>>>(dtb2, dub2, bscs2, A_log_T, A_log_R, ybuf);
    ln_kernel<<<1024, 256, 0, stream>>>(ybuf, xpeT, xpeR, ord, D_T, D_R, ln_g, ln_b, out);
}

// Round 16
// 206.291 us; speedup vs baseline: 1.7921x; 1.0294x over previous
//
#include <hip/hip_runtime.h>
#include <hip/hip_bf16.h>
#include <math.h>

// Problem constants
#define BATCH 2
#define DI 192          // D_INNER
#define NST 16          // D_STATE
#define DTR 6           // DT_RANK
#define KK 2
#define LL 4096
#define CT 512          // timesteps per scan chunk (8 per lane)
#define NCK (LL/CT)     // 8 chunk iterations

// ---------------- pe table + depth weight transpose (merged) ----------------
__global__ void pe_wt_kernel(float* __restrict__ pe,
                             const float* __restrict__ wde, const float* __restrict__ dpw,
                             const float* __restrict__ sgw, float* __restrict__ wtT) {
    if (blockIdx.x < 48) {
        int i = blockIdx.x * 256 + threadIdx.x;
        if (i >= 64 * DI) return;
        int col = i / DI, c = i % DI;
        float gx = (float)col / 63.f;
        int m = (c < 96) ? c : (c - 96);
        float invf = expf(-(float)m * (logf(10000.f) / 96.f));
        float ang = gx * invf;
        pe[i] = (c < 96) ? sinf(ang) : cosf(ang);
    } else {
        int idx = (blockIdx.x - 48) * 256 + threadIdx.x;
        if (idx < 192 * 272) {
            int i = idx / 272, j = idx % 272;
            float v;
            if (j < 192) v = wde[j * DI + i];
            else if (j < 256) v = dpw[(j - 192) * DI + i];
            else v = sgw[(j - 256) * DI + i];
            wtT[idx] = v;
        }
    }
}

// ---------------- fuse conv partials: grid (12 cgroups, 64 rows, 2 b) --------
__global__ void fusepm_part_kernel(const float* __restrict__ xT, const float* __restrict__ xR,
                                   const float* __restrict__ prox, const float* __restrict__ fw,
                                   float* __restrict__ pbuf) {
    __shared__ float wl[288];
    __shared__ float red[2][4][64];
    int cg = blockIdx.x;
    int row = blockIdx.y;
    int b = blockIdx.z;
    int tid = threadIdx.x;
    if (tid < 288) {
        int cl = (tid % 144) / 9, tap = tid % 9;
        int half = tid / 144;
        wl[tid] = fw[(half * DI + cg * 16 + cl) * 9 + tap];
    }
    __syncthreads();
    int px = tid & 63, g = tid >> 6;
    float aT = 0.f, aR = 0.f, aP = 0.f;
    #pragma unroll
    for (int cc = 0; cc < 4; ++cc) {
        int cl = g * 4 + cc;
        int c = cg * 16 + cl;
        const float* xTb = xT + (size_t)(b * DI + c) * LL;
        const float* xRb = xR + (size_t)(b * DI + c) * LL;
        const float* pb  = prox + (size_t)(b * DI + c) * LL;
        const float* wT = wl + cl * 9;
        const float* wP = wl + 144 + cl * 9;
        #pragma unroll
        for (int ky = 0; ky < 3; ++ky) {
            int yy = row + ky - 1;
            if (yy < 0 || yy > 63) continue;
            #pragma unroll
            for (int kx = 0; kx < 3; ++kx) {
                int xx = px + kx - 1;
                bool in = (xx >= 0 && xx < 64);
                int o = yy * 64 + (in ? xx : 0);
                float mT = in ? xTb[o] : 0.f;
                float mR = in ? xRb[o] : 0.f;
                float mP = in ? pb[o] : 0.f;
                float wTv = wT[ky * 3 + kx], wPv = wP[ky * 3 + kx];
                aT += mT * wTv;
                aR += mR * wTv;
                aP += mP * wPv;
            }
        }
    }
    red[0][g][px] = aT + aP;
    red[1][g][px] = aR + aP;
    __syncthreads();
    if (tid < 128) {
        int X = tid >> 6, x = tid & 63;
        float s = red[X][0][x] + red[X][1][x] + red[X][2][x] + red[X][3][x];
        pbuf[(size_t)(cg * 4 + X * 2 + b) * LL + row * 64 + x] = s;
    }
}

// ---------------- rank-count argsort with inline 12-partial reduction --------
__global__ __launch_bounds__(256) void rank_sort_kernel(const float* __restrict__ pbuf,
                                                        const float* __restrict__ fb,
                                                        int* __restrict__ ord,
                                                        int* __restrict__ inv) {
    __shared__ unsigned int keys[LL];
    __shared__ int cnts[4][64];
    int Xb = blockIdx.y;
    int X = Xb >> 1;
    int tid = threadIdx.x;
    float bias = fb[0];
    for (int i = tid; i < LL; i += 256) {
        float v = bias;
        #pragma unroll
        for (int cg = 0; cg < 12; ++cg)
            v += pbuf[(size_t)(cg * 4 + Xb) * LL + i];
        if (X == 0) v = -v;                  // T branch: descending pm
        int bits = __float_as_int(v);
        keys[i] = (bits < 0) ? ~(unsigned)bits : ((unsigned)bits | 0x80000000u);
    }
    __syncthreads();
    int el = tid & 63;
    int q = tid >> 6;
    int e = blockIdx.x * 64 + el;
    unsigned ui = keys[e];
    int count = 0;
    int j0 = q * (LL / 4);
    #pragma unroll 4
    for (int j = j0; j < j0 + LL / 4; ++j) {
        unsigned uj = keys[j];
        count += (uj < ui) || (uj == ui && j < e);
    }
    cnts[q][el] = count;
    __syncthreads();
    if (tid < 64) {
        int rank = cnts[0][tid] + cnts[1][tid] + cnts[2][tid] + cnts[3][tid];
        int i = blockIdx.x * 64 + tid;
        ord[(size_t)Xb * LL + rank] = i;
        inv[(size_t)Xb * LL + i] = rank;
    }
}

// ---------------- transpose x_T and x_R -> (b,l,c) + pe, one dispatch --------
// grid (128, 6, 4): z = which*2 + b
__global__ void transpose_x_kernel(const float* __restrict__ xT, const float* __restrict__ xR,
                                   float* __restrict__ xpeT, float* __restrict__ xpeR,
                                   const float* __restrict__ pe) {
    __shared__ float tile[32][33];
    int which = blockIdx.z >> 1;
    int b = blockIdx.z & 1;
    const float* in = which ? xR : xT;
    float* out = which ? xpeR : xpeT;
    int l0 = blockIdx.x * 32, c0 = blockIdx.y * 32;
    int tx = threadIdx.x, ty = threadIdx.y;
    #pragma unroll
    for (int r = 0; r < 4; ++r) {
        int c = c0 + ty + r * 8;
        tile[ty + r * 8][tx] = in[(size_t)(b * DI + c) * LL + l0 + tx];
    }
    __syncthreads();
    #pragma unroll
    for (int r = 0; r < 4; ++r) {
        int l = l0 + ty + r * 8;
        int c = c0 + tx;
        float v = tile[tx][ty + r * 8] + pe[(l & 63) * DI + c];
        out[(size_t)(b * LL + l) * DI + c] = v;
    }
}

// ---------------- depth path: reads prox in native NCHW (no transpose) ------
__global__ __launch_bounds__(256) void depth_kernel(
        const float* __restrict__ prox, const float* __restrict__ wtT,
        const float* __restrict__ bde, const float* __restrict__ sgb,
        float* __restrict__ dproj, float* __restrict__ dsig) {
    __shared__ float pvs[8][DI];
    __shared__ float dfs[8][DI];
    int bl0 = blockIdx.x * 8;
    int b = bl0 >> 12;           // / 4096
    int l0 = bl0 & 4095;
    int tid = threadIdx.x;
    for (int t = tid; t < 8 * DI; t += 256) {
        int i = t >> 3, l = t & 7;
        pvs[l][i] = prox[((size_t)b * DI + i) * LL + l0 + l];
    }
    __syncthreads();
    if (tid < DI) {
        float acc[8];
        #pragma unroll
        for (int l = 0; l < 8; ++l) acc[l] = 0.f;
        const float* wp = wtT + tid;
        for (int i = 0; i < DI; ++i) {
            float w = wp[i * 272];
            #pragma unroll
            for (int l = 0; l < 8; ++l) acc[l] += w * pvs[l][i];
        }
        float bias = bde[tid];
        #pragma unroll
        for (int l = 0; l < 8; ++l) {
            float v = acc[l] + bias;
            dfs[l][tid] = (v > 0.f) ? v : 0.2f * v;
        }
    }
    __syncthreads();
    if (tid < 160) {
        int o = tid >> 1;
        int ph = (tid & 1) * 4;
        float acc[4] = {0.f, 0.f, 0.f, 0.f};
        const float* wp = wtT + 192 + o;
        for (int i = 0; i < DI; ++i) {
            float w = wp[i * 272];
            #pragma unroll
            for (int p = 0; p < 4; ++p) acc[p] += w * dfs[ph + p][i];
        }
        if (o < 64) {
            #pragma unroll
            for (int p = 0; p < 4; ++p)
                dproj[(size_t)(bl0 + ph + p) * 64 + o] = acc[p];
        } else {
            float bias = sgb[o - 64];
            #pragma unroll
            for (int p = 0; p < 4; ++p) {
                float v = acc[p] + bias;
                v = (v > 0.f) ? v : 0.2f * v;
                dsig[(size_t)(bl0 + ph + p) * NST + (o - 64)] = 1.f / (1.f + __expf(-v));
            }
        }
    }
}

// ---------------- project: BOTH branches, 32 positions/block, 512 threads ----
__global__ __launch_bounds__(512) void project_kernel(
        const float* __restrict__ xpeT, const float* __restrict__ xpeR,
        const int* __restrict__ ord,
        const float* __restrict__ xpw, const float* __restrict__ dtw,
        const float* __restrict__ dtb, const float* __restrict__ dproj,
        const float* __restrict__ dsig, float* __restrict__ dtb2,
        float* __restrict__ dub2, float* __restrict__ bscs2) {
    __shared__ float u[32][196];        // row stride 784B (16B aligned)
    __shared__ float dbl[32][40];
    __shared__ int jarr[32];
    int id = blockIdx.x;
    int chunk = id & 127;
    int k = (id >> 7) & 1;
    int b = (id >> 8) & 1;
    int X = id >> 9;
    const float* xpe = X ? xpeR : xpeT;
    int R = (X * 2 + b) * 2 + k;             // buffer row group [X][b][k]
    int s0 = chunk * 32;
    int tid = threadIdx.x;
    if (tid < 32) {
        int s = s0 + tid;
        jarr[tid] = ord[(size_t)(X * 2 + b) * LL + ((k == 0) ? s : (LL - 1 - s))];
    }
    __syncthreads();
    for (int t = tid; t < 32 * 48; t += 512) {
        int l = t / 48, i4 = t % 48;
        *(float4*)&u[l][i4 * 4] =
            *(const float4*)(xpe + (size_t)(b * LL + jarr[l]) * DI + i4 * 4);
    }
    __syncthreads();
    {
        int og = tid >> 5, sl = tid & 31;    // 16 og-groups x 32 sl
        const float* w0 = xpw + (size_t)(k * 38 + og) * DI;
        const float* w1 = w0 + 16 * DI;
        const float* w2 = w0 + 32 * DI;
        bool has2 = (og < 6);
        float a0 = 0.f, a1 = 0.f, a2 = 0.f;
        for (int i4 = 0; i4 < 48; ++i4) {
            float4 u4 = *(const float4*)&u[sl][i4 * 4];
            float4 x0 = *(const float4*)(w0 + i4 * 4);
            float4 x1 = *(const float4*)(w1 + i4 * 4);
            a0 += x0.x * u4.x + x0.y * u4.y + x0.z * u4.z + x0.w * u4.w;
            a1 += x1.x * u4.x + x1.y * u4.y + x1.z * u4.z + x1.w * u4.w;
            if (has2) {
                float4 x2 = *(const float4*)(w2 + i4 * 4);
                a2 += x2.x * u4.x + x2.y * u4.y + x2.z * u4.z + x2.w * u4.w;
            }
        }
        dbl[sl][og] = a0;
        dbl[sl][og + 16] = a1;
        if (has2) dbl[sl][og + 32] = a2;
    }
    __syncthreads();
    if (tid < 384) {
        int c = tid % 192;
        int h = tid / 192;                   // h=0: s 0..15, h=1: s 16..31
        float w[6];
        #pragma unroll
        for (int r = 0; r < 6; ++r) w[r] = dtw[(k * DI + c) * DTR + r];
        float bias = dtb[k * DI + c];
        float dtl[16], dul[16];
        #pragma unroll
        for (int sl = 0; sl < 16; ++sl) {
            int s = h * 16 + sl;
            float d = bias;
            #pragma unroll
            for (int r = 0; r < 6; ++r) d += w[r] * dbl[s][r];
            float sp = fmaxf(d, 0.f) + __logf(1.f + __expf(-fabsf(d)));
            dtl[sl] = sp;
            dul[sl] = sp * u[s][c];
        }
        size_t base = (size_t)(R * DI + c) * LL + s0 + h * 16;
        #pragma unroll
        for (int g = 0; g < 4; ++g) {
            *(float4*)(dtb2 + base + g * 4) =
                make_float4(dtl[g*4], dtl[g*4+1], dtl[g*4+2], dtl[g*4+3]);
            *(float4*)(dub2 + base + g * 4) =
                make_float4(dul[g*4], dul[g*4+1], dul[g*4+2], dul[g*4+3]);
        }
    }
    {
        int n = tid >> 5, sl = tid & 31;     // 16 n x 32 sl: 128B row writes
        int j = jarr[sl];
        float wv = dsig[(size_t)(b * LL + j) * NST + n];
        float Bo = dbl[sl][6 + n], Co = dbl[sl][22 + n];
        float Bd = dproj[(size_t)(b * LL + j) * 64 + k * 32 + n];
        float Cd = dproj[(size_t)(b * LL + j) * 64 + k * 32 + 16 + n];
        size_t sb = (size_t)(R * 32 + n) * LL + s0 + sl;
        bscs2[sb] = (1.f - wv) * Bo + wv * Bd;
        bscs2[sb + (size_t)16 * LL] = (1.f - wv) * Co + wv * Cd;
    }
}

// ---------------- fused scan (proven): 512 thr, 8 waves x 2 states -----------
__global__ __launch_bounds__(512, 6) void scan_fused_kernel(
        const float* __restrict__ dtb2, const float* __restrict__ dub2,
        const float* __restrict__ bscs2, const float* __restrict__ AlogT,
        const float* __restrict__ AlogR, float* __restrict__ y) {
    __shared__ float ypart[2][8][CT + 4];
    int id = blockIdx.x;
    int c = id % DI;
    int bkx = id / DI;                       // 0..7: X*4 + b*2 + k
    int X = bkx >> 2;
    int k = bkx & 1;
    const float* Alog = X ? AlogR : AlogT;
    int w = threadIdx.x >> 6;
    int t = threadIdx.x & 63;
    float A0 = -__expf(Alog[(k * DI + c) * NST + w]);
    float A1 = -__expf(Alog[(k * DI + c) * NST + w + 8]);
    size_t rowc = (size_t)(bkx * DI + c) * LL;
    const float* dtp = dtb2 + rowc;
    const float* dup = dub2 + rowc;
    const float* b0p = bscs2 + (size_t)(bkx * 32 + w) * LL;
    const float* c0p = b0p + (size_t)16 * LL;
    const float* b1p = b0p + (size_t)8 * LL;
    const float* c1p = c0p + (size_t)8 * LL;
    float* yrow = y + rowc;
    float Hc0 = 0.f, Hc1 = 0.f;
    int off = t * 8;
    for (int ck = 0; ck < NCK; ++ck) {
        int base = ck * CT;
        int o = base + off;
        float4 dA = *(const float4*)(dtp + o), dB = *(const float4*)(dtp + o + 4);
        float4 uA = *(const float4*)(dup + o), uB = *(const float4*)(dup + o + 4);
        float4 B0a = *(const float4*)(b0p + o), B0b = *(const float4*)(b0p + o + 4);
        float4 B1a = *(const float4*)(b1p + o), B1b = *(const float4*)(b1p + o + 4);
        float d[8]  = {dA.x, dA.y, dA.z, dA.w, dB.x, dB.y, dB.z, dB.w};
        float uu[8] = {uA.x, uA.y, uA.z, uA.w, uB.x, uB.y, uB.z, uB.w};
        float Bb0[8] = {B0a.x, B0a.y, B0a.z, B0a.w, B0b.x, B0b.y, B0b.z, B0b.w};
        float Bb1[8] = {B1a.x, B1a.y, B1a.z, B1a.w, B1b.x, B1b.y, B1b.z, B1b.w};
        float e0[8], e1[8], z0[8], z1[8];
        float S = 0.f, cb0 = 0.f, cb1 = 0.f;
        #pragma unroll
        for (int j = 0; j < 8; ++j) {
            e0[j] = __expf(d[j] * A0);
            e1[j] = __expf(d[j] * A1);
            z0[j] = uu[j] * Bb0[j];
            z1[j] = uu[j] * Bb1[j];
            S += d[j];
            cb0 = cb0 * e0[j] + z0[j];
            cb1 = cb1 * e1[j] + z1[j];
        }
        #pragma unroll
        for (int m = 1; m < 64; m <<= 1) {
            float sS = __shfl_up(S, m);
            float s0 = __shfl_up(cb0, m);
            float s1 = __shfl_up(cb1, m);
            if (t >= m) {
                cb0 += __expf(A0 * S) * s0;
                cb1 += __expf(A1 * S) * s1;
                S += sS;
            }
        }
        float Sf  = __shfl(S, 63);
        float b0f = __shfl(cb0, 63);
        float b1f = __shfl(cb1, 63);
        float Se  = __shfl_up(S, 1);
        float b0e = __shfl_up(cb0, 1);
        float b1e = __shfl_up(cb1, 1);
        if (t == 0) { Se = 0.f; b0e = 0.f; b1e = 0.f; }
        float h0 = __expf(A0 * Se) * Hc0 + b0e;
        float h1 = __expf(A1 * Se) * Hc1 + b1e;
        float nHc0 = __expf(A0 * Sf) * Hc0 + b0f;
        float nHc1 = __expf(A1 * Sf) * Hc1 + b1f;
        Hc0 = nHc0; Hc1 = nHc1;
        float4 C0a = *(const float4*)(c0p + o), C0b = *(const float4*)(c0p + o + 4);
        float4 C1a = *(const float4*)(c1p + o), C1b = *(const float4*)(c1p + o + 4);
        float Cc0[8] = {C0a.x, C0a.y, C0a.z, C0a.w, C0b.x, C0b.y, C0b.z, C0b.w};
        float Cc1[8] = {C1a.x, C1a.y, C1a.z, C1a.w, C1b.x, C1b.y, C1b.z, C1b.w};
        float yv[8];
        #pragma unroll
        for (int j = 0; j < 8; ++j) {
            h0 = h0 * e0[j] + z0[j];
            h1 = h1 * e1[j] + z1[j];
            yv[j] = h0 * Cc0[j] + h1 * Cc1[j];
        }
        *(float4*)&ypart[ck & 1][w][off] = make_float4(yv[0], yv[1], yv[2], yv[3]);
        *(float4*)&ypart[ck & 1][w][off + 4] = make_float4(yv[4], yv[5], yv[6], yv[7]);
        __syncthreads();
        if (threadIdx.x < 128) {
            int t4 = threadIdx.x * 4;
            float4 s = *(const float4*)&ypart[ck & 1][0][t4];
            #pragma unroll
            for (int r = 1; r < 8; ++r) {
                float4 v = *(const float4*)&ypart[ck & 1][r][t4];
                s.x += v.x; s.y += v.y; s.z += v.z; s.w += v.w;
            }
            *(float4*)(yrow + base + t4) = s;
        }
    }
}

// ---------------- s-order gather + D*u + layernorm + output, both branches ---
__global__ __launch_bounds__(256) void ln_kernel(const float* __restrict__ y,
                          const float* __restrict__ xpeT, const float* __restrict__ xpeR,
                          const int* __restrict__ ord, const float* __restrict__ DvT,
                          const float* __restrict__ DvR, const float* __restrict__ g,
                          const float* __restrict__ beta, float* __restrict__ out) {
    __shared__ float y0t[DI][17];
    __shared__ float y1t[DI][17];
    int id = blockIdx.x;
    int X = id >> 9;
    int b = (id >> 8) & 1;
    int s0 = (id & 255) * 16;
    const float* xpe = X ? xpeR : xpeT;
    const float* Dvec = X ? DvR : DvT;
    int R0 = (X * 2 + b) * 2;
    int tid = threadIdx.x;
    for (int idx = tid; idx < DI * 16; idx += 256) {
        int c = idx >> 4, j = idx & 15;
        y0t[c][j] = y[((size_t)(R0 + 0) * DI + c) * LL + s0 + j];
        y1t[c][j] = y[((size_t)(R0 + 1) * DI + c) * LL + (LL - 1 - s0 - j)];
    }
    __syncthreads();
    int w = tid >> 6, lane = tid & 63;
    #pragma unroll
    for (int it = 0; it < 4; ++it) {
        int j = it * 4 + w;
        int l = ord[(size_t)(X * 2 + b) * LL + s0 + j];
        const float* xr = xpe + (size_t)(b * LL + l) * DI;
        float v[3];
        float sum = 0.f, sq = 0.f;
        #pragma unroll
        for (int r = 0; r < 3; ++r) {
            int c = lane + r * 64;
            float t = y0t[c][j] + y1t[c][j] + (Dvec[c] + Dvec[DI + c]) * xr[c];
            v[r] = t; sum += t; sq += t * t;
        }
        #pragma unroll
        for (int m = 1; m < 64; m <<= 1) {
            sum += __shfl_xor(sum, m);
            sq += __shfl_xor(sq, m);
        }
        float mu = sum * (1.f / 192.f);
        float var = sq * (1.f / 192.f) - mu * mu;
        float rs = rsqrtf(var + 1e-5f);
        float* op = out + ((size_t)(X * 2 + b) * LL + l) * DI;
        #pragma unroll
        for (int r = 0; r < 3; ++r) {
            int c = lane + r * 64;
            op[c] = (v[r] - mu) * rs * g[c] + beta[c];
        }
    }
}

extern "C" void kernel_launch(void* const* d_in, const int* in_sizes, int n_in,
                              void* d_out, int out_size, void* d_ws, size_t ws_size,
                              hipStream_t stream) {
    const float* x_T = (const float*)d_in[0];
    const float* x_R = (const float*)d_in[1];
    const float* prox = (const float*)d_in[2];
    const float* fuse_w = (const float*)d_in[3];
    const float* fuse_b = (const float*)d_in[4];
    const float* x_proj_w = (const float*)d_in[5];
    const float* dt_w = (const float*)d_in[6];
    const float* dt_b = (const float*)d_in[7];
    const float* A_log_T = (const float*)d_in[8];
    const float* A_log_R = (const float*)d_in[9];
    const float* D_T = (const float*)d_in[10];
    const float* D_R = (const float*)d_in[11];
    const float* depth_enc_w = (const float*)d_in[12];
    const float* depth_enc_b = (const float*)d_in[13];
    const float* depth_proj_w = (const float*)d_in[14];
    const float* sig_w = (const float*)d_in[15];
    const float* sig_b = (const float*)d_in[16];
    const float* ln_g = (const float*)d_in[17];
    const float* ln_b = (const float*)d_in[18];
    float* out = (float*)d_out;
    char* ws = (char*)d_ws;

    // ws_size = 256 MiB. Layout:
    float* pe    = (float*)(ws + 0);         //    49152
    int*   ord   = (int*)(ws + 114688);      //    65536
    int*   inv   = (int*)(ws + 180224);      //    65536
    float* xpeR  = (float*)(ws + 245760);    //  6291456
    float* dproj = (float*)(ws + 6537216);   //  2097152
    float* dsig  = (float*)(ws + 8634368);   //   524288
    float* xpeT  = (float*)(ws + 9158656);   //  6291456
    float* dtb2  = (float*)(ws + 15450112);  // 25165824  [X][b][k][c][s]
    float* dub2  = (float*)(ws + 40615936);  // 25165824
    float* bscs2 = (float*)(ws + 65781760);  //  4194304  [X][b][k][n][s]
    float* ybuf  = (float*)(ws + 69976064);  // 25165824  [X][b][k][c][s]
    float* pbuf  = dtb2;                     // fuse partials (dead until project)
    float* wtT   = bscs2;                    // 209 KB (dead once project writes)

    pe_wt_kernel<<<252, 256, 0, stream>>>(pe, depth_enc_w, depth_proj_w, sig_w, wtT);
    fusepm_part_kernel<<<dim3(12, 64, 2), 256, 0, stream>>>(x_T, x_R, prox, fuse_w, pbuf);
    rank_sort_kernel<<<dim3(64, 4), 256, 0, stream>>>(pbuf, fuse_b, ord, inv);
    depth_kernel<<<1024, 256, 0, stream>>>(prox, wtT, depth_enc_b, sig_b, dproj, dsig);
    transpose_x_kernel<<<dim3(128, 6, 4), dim3(32, 8), 0, stream>>>(x_T, x_R, xpeT, xpeR, pe);
    project_kernel<<<1024, 512, 0, stream>>>(xpeT, xpeR, ord, x_proj_w, dt_w, dt_b,
                                             dproj, dsig, dtb2, dub2, bscs2);
    scan_fused_kernel<<<8 * DI, 512, 0, stream>>>(dtb2, dub2, bscs2, A_log_T, A_log_R, ybuf);
    ln_kernel<<<1024, 256, 0, stream>>>(ybuf, xpeT, xpeR, ord, D_T, D_R, ln_g, ln_b, out);
}

// Round 17
// 177.841 us; speedup vs baseline: 2.0788x; 1.1600x over previous
//
#include <hip/hip_runtime.h>
#include <hip/hip_bf16.h>
#include <math.h>

// Problem constants
#define BATCH 2
#define DI 192          // D_INNER
#define NST 16          // D_STATE
#define DTR 6           // DT_RANK
#define KK 2
#define LL 4096
#define CT 512          // timesteps per scan chunk (8 per lane)
#define NCK (LL/CT)     // 8 chunk iterations

// ================= dispatch 1: pe + wtT + fuse-conv partials =================
// blocks 0..47: pe; 48..251: wtT; 252..1787: fusepm partials
__global__ __launch_bounds__(256) void prep_kernel(
        float* __restrict__ pe,
        const float* __restrict__ wde, const float* __restrict__ dpw,
        const float* __restrict__ sgw, float* __restrict__ wtT,
        const float* __restrict__ xT, const float* __restrict__ xR,
        const float* __restrict__ prox, const float* __restrict__ fw,
        float* __restrict__ pbuf) {
    __shared__ float wl[288];
    __shared__ float red[2][4][64];
    int bid = blockIdx.x;
    int tid = threadIdx.x;
    if (bid < 48) {
        int i = bid * 256 + tid;
        if (i >= 64 * DI) return;
        int col = i / DI, c = i % DI;
        float gx = (float)col / 63.f;
        int m = (c < 96) ? c : (c - 96);
        float invf = expf(-(float)m * (logf(10000.f) / 96.f));
        float ang = gx * invf;
        pe[i] = (c < 96) ? sinf(ang) : cosf(ang);
        return;
    }
    if (bid < 252) {
        int idx = (bid - 48) * 256 + tid;
        if (idx < 192 * 272) {
            int i = idx / 272, j = idx % 272;
            float v;
            if (j < 192) v = wde[j * DI + i];
            else if (j < 256) v = dpw[(j - 192) * DI + i];
            else v = sgw[(j - 256) * DI + i];
            wtT[idx] = v;
        }
        return;
    }
    // fusepm partials: fid -> (cg, row, b), identical math to prior rounds
    int fid = bid - 252;
    int cg = fid >> 7;            // /128
    int rem = fid & 127;
    int row = rem >> 1;
    int b = rem & 1;
    if (tid < 288) {
        int cl = (tid % 144) / 9, tap = tid % 9;
        int half = tid / 144;
        wl[tid] = fw[(half * DI + cg * 16 + cl) * 9 + tap];
    }
    __syncthreads();
    int px = tid & 63, g = tid >> 6;
    float aT = 0.f, aR = 0.f, aP = 0.f;
    #pragma unroll
    for (int cc = 0; cc < 4; ++cc) {
        int cl = g * 4 + cc;
        int c = cg * 16 + cl;
        const float* xTb = xT + (size_t)(b * DI + c) * LL;
        const float* xRb = xR + (size_t)(b * DI + c) * LL;
        const float* pb  = prox + (size_t)(b * DI + c) * LL;
        const float* wT = wl + cl * 9;
        const float* wP = wl + 144 + cl * 9;
        #pragma unroll
        for (int ky = 0; ky < 3; ++ky) {
            int yy = row + ky - 1;
            if (yy < 0 || yy > 63) continue;
            #pragma unroll
            for (int kx = 0; kx < 3; ++kx) {
                int xx = px + kx - 1;
                bool in = (xx >= 0 && xx < 64);
                int o = yy * 64 + (in ? xx : 0);
                float mT = in ? xTb[o] : 0.f;
                float mR = in ? xRb[o] : 0.f;
                float mP = in ? pb[o] : 0.f;
                float wTv = wT[ky * 3 + kx], wPv = wP[ky * 3 + kx];
                aT += mT * wTv;
                aR += mR * wTv;
                aP += mP * wPv;
            }
        }
    }
    red[0][g][px] = aT + aP;
    red[1][g][px] = aR + aP;
    __syncthreads();
    if (tid < 128) {
        int X = tid >> 6, x = tid & 63;
        float s = red[X][0][x] + red[X][1][x] + red[X][2][x] + red[X][3][x];
        pbuf[(size_t)(cg * 4 + X * 2 + b) * LL + row * 64 + x] = s;
    }
}

// ================= dispatch 2: rank_sort + depth + x-transposes ==============
// blocks 0..255: rank_sort; 256..1279: depth; 1280..4351: transpose_x
union MidSmem {
    struct { unsigned int keys[LL]; int cnts[4][64]; } srt;   // 17.4 KB
    struct { float pvs[8][DI]; float dfs[8][DI]; } dep;       // 12.3 KB
    struct { float tile[32][33]; } trp;                       //  4.2 KB
};

__global__ __launch_bounds__(256) void mid_kernel(
        const float* __restrict__ pbuf, const float* __restrict__ fb,
        int* __restrict__ ord,
        const float* __restrict__ prox, const float* __restrict__ wtT,
        const float* __restrict__ bde, const float* __restrict__ sgb,
        float* __restrict__ dproj, float* __restrict__ dsig,
        const float* __restrict__ xT, const float* __restrict__ xR,
        float* __restrict__ xpeT, float* __restrict__ xpeR,
        const float* __restrict__ pe) {
    __shared__ MidSmem sm;
    int bid = blockIdx.x;
    int tid = threadIdx.x;
    if (bid < 256) {
        // ---- rank-count argsort with inline 12-partial reduction ----
        int eblk = bid & 63;
        int Xb = bid >> 6;
        int X = Xb >> 1;
        float bias = fb[0];
        for (int i = tid; i < LL; i += 256) {
            float v = bias;
            #pragma unroll
            for (int cg = 0; cg < 12; ++cg)
                v += pbuf[(size_t)(cg * 4 + Xb) * LL + i];
            if (X == 0) v = -v;              // T branch: descending pm
            int bits = __float_as_int(v);
            sm.srt.keys[i] = (bits < 0) ? ~(unsigned)bits : ((unsigned)bits | 0x80000000u);
        }
        __syncthreads();
        int el = tid & 63;
        int q = tid >> 6;
        int e = eblk * 64 + el;
        unsigned ui = sm.srt.keys[e];
        int count = 0;
        int j0 = q * (LL / 4);
        #pragma unroll 4
        for (int j = j0; j < j0 + LL / 4; ++j) {
            unsigned uj = sm.srt.keys[j];
            count += (uj < ui) || (uj == ui && j < e);
        }
        sm.srt.cnts[q][el] = count;
        __syncthreads();
        if (tid < 64) {
            int rank = sm.srt.cnts[0][tid] + sm.srt.cnts[1][tid] +
                       sm.srt.cnts[2][tid] + sm.srt.cnts[3][tid];
            int i = eblk * 64 + tid;
            ord[(size_t)Xb * LL + rank] = i;
        }
        return;
    }
    if (bid < 1280) {
        // ---- depth path: 8 positions/block, native NCHW prox reads ----
        int bl0 = (bid - 256) * 8;
        int b = bl0 >> 12;
        int l0 = bl0 & 4095;
        for (int t = tid; t < 8 * DI; t += 256) {
            int i = t >> 3, l = t & 7;
            sm.dep.pvs[l][i] = prox[((size_t)b * DI + i) * LL + l0 + l];
        }
        __syncthreads();
        if (tid < DI) {
            float acc[8];
            #pragma unroll
            for (int l = 0; l < 8; ++l) acc[l] = 0.f;
            const float* wp = wtT + tid;
            for (int i = 0; i < DI; ++i) {
                float w = wp[i * 272];
                #pragma unroll
                for (int l = 0; l < 8; ++l) acc[l] += w * sm.dep.pvs[l][i];
            }
            float bias = bde[tid];
            #pragma unroll
            for (int l = 0; l < 8; ++l) {
                float v = acc[l] + bias;
                sm.dep.dfs[l][tid] = (v > 0.f) ? v : 0.2f * v;
            }
        }
        __syncthreads();
        if (tid < 160) {
            int o = tid >> 1;
            int ph = (tid & 1) * 4;
            float acc[4] = {0.f, 0.f, 0.f, 0.f};
            const float* wp = wtT + 192 + o;
            for (int i = 0; i < DI; ++i) {
                float w = wp[i * 272];
                #pragma unroll
                for (int p = 0; p < 4; ++p) acc[p] += w * sm.dep.dfs[ph + p][i];
            }
            if (o < 64) {
                #pragma unroll
                for (int p = 0; p < 4; ++p)
                    dproj[(size_t)(bl0 + ph + p) * 64 + o] = acc[p];
            } else {
                float bias = sgb[o - 64];
                #pragma unroll
                for (int p = 0; p < 4; ++p) {
                    float v = acc[p] + bias;
                    v = (v > 0.f) ? v : 0.2f * v;
                    dsig[(size_t)(bl0 + ph + p) * NST + (o - 64)] = 1.f / (1.f + __expf(-v));
                }
            }
        }
        return;
    }
    {
        // ---- transpose x_T/x_R -> (b,l,c) + pe ----
        int tbid = bid - 1280;               // 0..3071
        int lx = tbid & 127;
        int cy = (tbid >> 7) % 6;
        int z = tbid / 768;                  // which*2 + b
        int which = z >> 1;
        int b = z & 1;
        const float* in = which ? xR : xT;
        float* out = which ? xpeR : xpeT;
        int l0 = lx * 32, c0 = cy * 32;
        int tx = tid & 31, ty = tid >> 5;
        #pragma unroll
        for (int r = 0; r < 4; ++r) {
            int c = c0 + ty + r * 8;
            sm.trp.tile[ty + r * 8][tx] = in[(size_t)(b * DI + c) * LL + l0 + tx];
        }
        __syncthreads();
        #pragma unroll
        for (int r = 0; r < 4; ++r) {
            int l = l0 + ty + r * 8;
            int c = c0 + tx;
            float v = sm.trp.tile[tx][ty + r * 8] + pe[(l & 63) * DI + c];
            out[(size_t)(b * LL + l) * DI + c] = v;
        }
    }
}

// ---------------- project: BOTH branches, 32 positions/block, 512 threads ----
__global__ __launch_bounds__(512) void project_kernel(
        const float* __restrict__ xpeT, const float* __restrict__ xpeR,
        const int* __restrict__ ord,
        const float* __restrict__ xpw, const float* __restrict__ dtw,
        const float* __restrict__ dtb, const float* __restrict__ dproj,
        const float* __restrict__ dsig, float* __restrict__ dtb2,
        float* __restrict__ dub2, float* __restrict__ bscs2) {
    __shared__ float u[32][196];        // row stride 784B (16B aligned)
    __shared__ float dbl[32][40];
    __shared__ int jarr[32];
    int id = blockIdx.x;
    int chunk = id & 127;
    int k = (id >> 7) & 1;
    int b = (id >> 8) & 1;
    int X = id >> 9;
    const float* xpe = X ? xpeR : xpeT;
    int R = (X * 2 + b) * 2 + k;             // buffer row group [X][b][k]
    int s0 = chunk * 32;
    int tid = threadIdx.x;
    if (tid < 32) {
        int s = s0 + tid;
        jarr[tid] = ord[(size_t)(X * 2 + b) * LL + ((k == 0) ? s : (LL - 1 - s))];
    }
    __syncthreads();
    for (int t = tid; t < 32 * 48; t += 512) {
        int l = t / 48, i4 = t % 48;
        *(float4*)&u[l][i4 * 4] =
            *(const float4*)(xpe + (size_t)(b * LL + jarr[l]) * DI + i4 * 4);
    }
    __syncthreads();
    {
        int og = tid >> 5, sl = tid & 31;    // 16 og-groups x 32 sl
        const float* w0 = xpw + (size_t)(k * 38 + og) * DI;
        const float* w1 = w0 + 16 * DI;
        const float* w2 = w0 + 32 * DI;
        bool has2 = (og < 6);
        float a0 = 0.f, a1 = 0.f, a2 = 0.f;
        for (int i4 = 0; i4 < 48; ++i4) {
            float4 u4 = *(const float4*)&u[sl][i4 * 4];
            float4 x0 = *(const float4*)(w0 + i4 * 4);
            float4 x1 = *(const float4*)(w1 + i4 * 4);
            a0 += x0.x * u4.x + x0.y * u4.y + x0.z * u4.z + x0.w * u4.w;
            a1 += x1.x * u4.x + x1.y * u4.y + x1.z * u4.z + x1.w * u4.w;
            if (has2) {
                float4 x2 = *(const float4*)(w2 + i4 * 4);
                a2 += x2.x * u4.x + x2.y * u4.y + x2.z * u4.z + x2.w * u4.w;
            }
        }
        dbl[sl][og] = a0;
        dbl[sl][og + 16] = a1;
        if (has2) dbl[sl][og + 32] = a2;
    }
    __syncthreads();
    if (tid < 384) {
        int c = tid % 192;
        int h = tid / 192;                   // h=0: s 0..15, h=1: s 16..31
        float w[6];
        #pragma unroll
        for (int r = 0; r < 6; ++r) w[r] = dtw[(k * DI + c) * DTR + r];
        float bias = dtb[k * DI + c];
        float dtl[16], dul[16];
        #pragma unroll
        for (int sl = 0; sl < 16; ++sl) {
            int s = h * 16 + sl;
            float d = bias;
            #pragma unroll
            for (int r = 0; r < 6; ++r) d += w[r] * dbl[s][r];
            float sp = fmaxf(d, 0.f) + __logf(1.f + __expf(-fabsf(d)));
            dtl[sl] = sp;
            dul[sl] = sp * u[s][c];
        }
        size_t base = (size_t)(R * DI + c) * LL + s0 + h * 16;
        #pragma unroll
        for (int g = 0; g < 4; ++g) {
            *(float4*)(dtb2 + base + g * 4) =
                make_float4(dtl[g*4], dtl[g*4+1], dtl[g*4+2], dtl[g*4+3]);
            *(float4*)(dub2 + base + g * 4) =
                make_float4(dul[g*4], dul[g*4+1], dul[g*4+2], dul[g*4+3]);
        }
    }
    {
        int n = tid >> 5, sl = tid & 31;     // 16 n x 32 sl: 128B row writes
        int j = jarr[sl];
        float wv = dsig[(size_t)(b * LL + j) * NST + n];
        float Bo = dbl[sl][6 + n], Co = dbl[sl][22 + n];
        float Bd = dproj[(size_t)(b * LL + j) * 64 + k * 32 + n];
        float Cd = dproj[(size_t)(b * LL + j) * 64 + k * 32 + 16 + n];
        size_t sb = (size_t)(R * 32 + n) * LL + s0 + sl;
        bscs2[sb] = (1.f - wv) * Bo + wv * Bd;
        bscs2[sb + (size_t)16 * LL] = (1.f - wv) * Co + wv * Cd;
    }
}

// ---------------- fused scan (proven): 512 thr, 8 waves x 2 states -----------
__global__ __launch_bounds__(512, 6) void scan_fused_kernel(
        const float* __restrict__ dtb2, const float* __restrict__ dub2,
        const float* __restrict__ bscs2, const float* __restrict__ AlogT,
        const float* __restrict__ AlogR, float* __restrict__ y) {
    __shared__ float ypart[2][8][CT + 4];
    int id = blockIdx.x;
    int c = id % DI;
    int bkx = id / DI;                       // 0..7: X*4 + b*2 + k
    int X = bkx >> 2;
    int k = bkx & 1;
    const float* Alog = X ? AlogR : AlogT;
    int w = threadIdx.x >> 6;
    int t = threadIdx.x & 63;
    float A0 = -__expf(Alog[(k * DI + c) * NST + w]);
    float A1 = -__expf(Alog[(k * DI + c) * NST + w + 8]);
    size_t rowc = (size_t)(bkx * DI + c) * LL;
    const float* dtp = dtb2 + rowc;
    const float* dup = dub2 + rowc;
    const float* b0p = bscs2 + (size_t)(bkx * 32 + w) * LL;
    const float* c0p = b0p + (size_t)16 * LL;
    const float* b1p = b0p + (size_t)8 * LL;
    const float* c1p = c0p + (size_t)8 * LL;
    float* yrow = y + rowc;
    float Hc0 = 0.f, Hc1 = 0.f;
    int off = t * 8;
    for (int ck = 0; ck < NCK; ++ck) {
        int base = ck * CT;
        int o = base + off;
        float4 dA = *(const float4*)(dtp + o), dB = *(const float4*)(dtp + o + 4);
        float4 uA = *(const float4*)(dup + o), uB = *(const float4*)(dup + o + 4);
        float4 B0a = *(const float4*)(b0p + o), B0b = *(const float4*)(b0p + o + 4);
        float4 B1a = *(const float4*)(b1p + o), B1b = *(const float4*)(b1p + o + 4);
        float d[8]  = {dA.x, dA.y, dA.z, dA.w, dB.x, dB.y, dB.z, dB.w};
        float uu[8] = {uA.x, uA.y, uA.z, uA.w, uB.x, uB.y, uB.z, uB.w};
        float Bb0[8] = {B0a.x, B0a.y, B0a.z, B0a.w, B0b.x, B0b.y, B0b.z, B0b.w};
        float Bb1[8] = {B1a.x, B1a.y, B1a.z, B1a.w, B1b.x, B1b.y, B1b.z, B1b.w};
        float e0[8], e1[8], z0[8], z1[8];
        float S = 0.f, cb0 = 0.f, cb1 = 0.f;
        #pragma unroll
        for (int j = 0; j < 8; ++j) {
            e0[j] = __expf(d[j] * A0);
            e1[j] = __expf(d[j] * A1);
            z0[j] = uu[j] * Bb0[j];
            z1[j] = uu[j] * Bb1[j];
            S += d[j];
            cb0 = cb0 * e0[j] + z0[j];
            cb1 = cb1 * e1[j] + z1[j];
        }
        #pragma unroll
        for (int m = 1; m < 64; m <<= 1) {
            float sS = __shfl_up(S, m);
            float s0 = __shfl_up(cb0, m);
            float s1 = __shfl_up(cb1, m);
            if (t >= m) {
                cb0 += __expf(A0 * S) * s0;
                cb1 += __expf(A1 * S) * s1;
                S += sS;
            }
        }
        float Sf  = __shfl(S, 63);
        float b0f = __shfl(cb0, 63);
        float b1f = __shfl(cb1, 63);
        float Se  = __shfl_up(S, 1);
        float b0e = __shfl_up(cb0, 1);
        float b1e = __shfl_up(cb1, 1);
        if (t == 0) { Se = 0.f; b0e = 0.f; b1e = 0.f; }
        float h0 = __expf(A0 * Se) * Hc0 + b0e;
        float h1 = __expf(A1 * Se) * Hc1 + b1e;
        float nHc0 = __expf(A0 * Sf) * Hc0 + b0f;
        float nHc1 = __expf(A1 * Sf) * Hc1 + b1f;
        Hc0 = nHc0; Hc1 = nHc1;
        float4 C0a = *(const float4*)(c0p + o), C0b = *(const float4*)(c0p + o + 4);
        float4 C1a = *(const float4*)(c1p + o), C1b = *(const float4*)(c1p + o + 4);
        float Cc0[8] = {C0a.x, C0a.y, C0a.z, C0a.w, C0b.x, C0b.y, C0b.z, C0b.w};
        float Cc1[8] = {C1a.x, C1a.y, C1a.z, C1a.w, C1b.x, C1b.y, C1b.z, C1b.w};
        float yv[8];
        #pragma unroll
        for (int j = 0; j < 8; ++j) {
            h0 = h0 * e0[j] + z0[j];
            h1 = h1 * e1[j] + z1[j];
            yv[j] = h0 * Cc0[j] + h1 * Cc1[j];
        }
        *(float4*)&ypart[ck & 1][w][off] = make_float4(yv[0], yv[1], yv[2], yv[3]);
        *(float4*)&ypart[ck & 1][w][off + 4] = make_float4(yv[4], yv[5], yv[6], yv[7]);
        __syncthreads();
        if (threadIdx.x < 128) {
            int t4 = threadIdx.x * 4;
            float4 s = *(const float4*)&ypart[ck & 1][0][t4];
            #pragma unroll
            for (int r = 1; r < 8; ++r) {
                float4 v = *(const float4*)&ypart[ck & 1][r][t4];
                s.x += v.x; s.y += v.y; s.z += v.z; s.w += v.w;
            }
            *(float4*)(yrow + base + t4) = s;
        }
    }
}

// ---------------- s-order gather + D*u + layernorm + output, both branches ---
__global__ __launch_bounds__(256) void ln_kernel(const float* __restrict__ y,
                          const float* __restrict__ xpeT, const float* __restrict__ xpeR,
                          const int* __restrict__ ord, const float* __restrict__ DvT,
                          const float* __restrict__ DvR, const float* __restrict__ g,
                          const float* __restrict__ beta, float* __restrict__ out) {
    __shared__ float y0t[DI][17];
    __shared__ float y1t[DI][17];
    int id = blockIdx.x;
    int X = id >> 9;
    int b = (id >> 8) & 1;
    int s0 = (id & 255) * 16;
    const float* xpe = X ? xpeR : xpeT;
    const float* Dvec = X ? DvR : DvT;
    int R0 = (X * 2 + b) * 2;
    int tid = threadIdx.x;
    for (int idx = tid; idx < DI * 16; idx += 256) {
        int c = idx >> 4, j = idx & 15;
        y0t[c][j] = y[((size_t)(R0 + 0) * DI + c) * LL + s0 + j];
        y1t[c][j] = y[((size_t)(R0 + 1) * DI + c) * LL + (LL - 1 - s0 - j)];
    }
    __syncthreads();
    int w = tid >> 6, lane = tid & 63;
    #pragma unroll
    for (int it = 0; it < 4; ++it) {
        int j = it * 4 + w;
        int l = ord[(size_t)(X * 2 + b) * LL + s0 + j];
        const float* xr = xpe + (size_t)(b * LL + l) * DI;
        float v[3];
        float sum = 0.f, sq = 0.f;
        #pragma unroll
        for (int r = 0; r < 3; ++r) {
            int c = lane + r * 64;
            float t = y0t[c][j] + y1t[c][j] + (Dvec[c] + Dvec[DI + c]) * xr[c];
            v[r] = t; sum += t; sq += t * t;
        }
        #pragma unroll
        for (int m = 1; m < 64; m <<= 1) {
            sum += __shfl_xor(sum, m);
            sq += __shfl_xor(sq, m);
        }
        float mu = sum * (1.f / 192.f);
        float var = sq * (1.f / 192.f) - mu * mu;
        float rs = rsqrtf(var + 1e-5f);
        float* op = out + ((size_t)(X * 2 + b) * LL + l) * DI;
        #pragma unroll
        for (int r = 0; r < 3; ++r) {
            int c = lane + r * 64;
            op[c] = (v[r] - mu) * rs * g[c] + beta[c];
        }
    }
}

extern "C" void kernel_launch(void* const* d_in, const int* in_sizes, int n_in,
                              void* d_out, int out_size, void* d_ws, size_t ws_size,
                              hipStream_t stream) {
    const float* x_T = (const float*)d_in[0];
    const float* x_R = (const float*)d_in[1];
    const float* prox = (const float*)d_in[2];
    const float* fuse_w = (const float*)d_in[3];
    const float* fuse_b = (const float*)d_in[4];
    const float* x_proj_w = (const float*)d_in[5];
    const float* dt_w = (const float*)d_in[6];
    const float* dt_b = (const float*)d_in[7];
    const float* A_log_T = (const float*)d_in[8];
    const float* A_log_R = (const float*)d_in[9];
    const float* D_T = (const float*)d_in[10];
    const float* D_R = (const float*)d_in[11];
    const float* depth_enc_w = (const float*)d_in[12];
    const float* depth_enc_b = (const float*)d_in[13];
    const float* depth_proj_w = (const float*)d_in[14];
    const float* sig_w = (const float*)d_in[15];
    const float* sig_b = (const float*)d_in[16];
    const float* ln_g = (const float*)d_in[17];
    const float* ln_b = (const float*)d_in[18];
    float* out = (float*)d_out;
    char* ws = (char*)d_ws;

    // ws_size = 256 MiB. Layout:
    float* pe    = (float*)(ws + 0);         //    49152
    int*   ord   = (int*)(ws + 114688);      //    65536
    float* xpeR  = (float*)(ws + 245760);    //  6291456
    float* dproj = (float*)(ws + 6537216);   //  2097152
    float* dsig  = (float*)(ws + 8634368);   //   524288
    float* xpeT  = (float*)(ws + 9158656);   //  6291456
    float* dtb2  = (float*)(ws + 15450112);  // 25165824  [X][b][k][c][s]
    float* dub2  = (float*)(ws + 40615936);  // 25165824
    float* bscs2 = (float*)(ws + 65781760);  //  4194304  [X][b][k][n][s]
    float* ybuf  = (float*)(ws + 69976064);  // 25165824  [X][b][k][c][s]
    float* pbuf  = dtb2;                     // fuse partials (dead until project)
    float* wtT   = bscs2;                    // 209 KB (dead once project writes)

    prep_kernel<<<1788, 256, 0, stream>>>(pe, depth_enc_w, depth_proj_w, sig_w, wtT,
                                          x_T, x_R, prox, fuse_w, pbuf);
    mid_kernel<<<4352, 256, 0, stream>>>(pbuf, fuse_b, ord, prox, wtT,
                                         depth_enc_b, sig_b, dproj, dsig,
                                         x_T, x_R, xpeT, xpeR, pe);
    project_kernel<<<1024, 512, 0, stream>>>(xpeT, xpeR, ord, x_proj_w, dt_w, dt_b,
                                             dproj, dsig, dtb2, dub2, bscs2);
    scan_fused_kernel<<<8 * DI, 512, 0, stream>>>(dtb2, dub2, bscs2, A_log_T, A_log_R, ybuf);
    ln_kernel<<<1024, 256, 0, stream>>>(ybuf, xpeT, xpeR, ord, D_T, D_R, ln_g, ln_b, out);
}